// Round 6
// baseline (1602.094 us; speedup 1.0000x reference)
//
#include <hip/hip_runtime.h>
#include <hip/hip_bf16.h>
#include <hip/hip_fp16.h>

#define NN    50000
#define NE    800000
#define ETOT  (NE + NN)
#define D     128
#define NB    ((NN + 255) / 256)   // scan blocks

__device__ __forceinline__ float gelu_tanh(float x) {
    float x3 = x * x * x;
    float t  = tanhf(0.7978845608028654f * (x + 0.044715f * x3));
    return 0.5f * x * (1.0f + t);
}

__device__ __forceinline__ float rdlane(float v, int l) {
    return __int_as_float(__builtin_amdgcn_readlane(__float_as_int(v), l));
}

// ---------------- CSR build ----------------

__global__ void count_k(const int* __restrict__ dstarr, int* __restrict__ counts) {
    int e = blockIdx.x * blockDim.x + threadIdx.x;
    if (e >= ETOT) return;
    int d = (e < NE) ? dstarr[e] : (e - NE);
    atomicAdd(&counts[d], 1);
}

__global__ void scan1_k(const int* __restrict__ counts, int* __restrict__ blk_sums) {
    __shared__ int sm[4];
    int i = blockIdx.x * 256 + threadIdx.x;
    int v = (i < NN) ? counts[i] : 0;
    #pragma unroll
    for (int o = 32; o; o >>= 1) v += __shfl_xor(v, o);
    if ((threadIdx.x & 63) == 0) sm[threadIdx.x >> 6] = v;
    __syncthreads();
    if (threadIdx.x == 0) blk_sums[blockIdx.x] = sm[0] + sm[1] + sm[2] + sm[3];
}

__global__ void scan2_k(const int* __restrict__ blk_sums, int* __restrict__ blk_offs,
                        int* __restrict__ row_ptr) {
    if (threadIdx.x == 0 && blockIdx.x == 0) {
        int acc = 0;
        for (int b = 0; b < NB; ++b) { blk_offs[b] = acc; acc += blk_sums[b]; }
        row_ptr[NN] = acc;
    }
}

__global__ void scan3_k(const int* __restrict__ counts, const int* __restrict__ blk_offs,
                        int* __restrict__ row_ptr, int* __restrict__ write_ptr) {
    __shared__ int s[256];
    int t = threadIdx.x;
    int i = blockIdx.x * 256 + t;
    int v = (i < NN) ? counts[i] : 0;
    s[t] = v;
    __syncthreads();
    for (int off = 1; off < 256; off <<= 1) {
        int x = (t >= off) ? s[t - off] : 0;
        __syncthreads();
        s[t] += x;
        __syncthreads();
    }
    int excl = s[t] - v + blk_offs[blockIdx.x];
    if (i < NN) { row_ptr[i] = excl; write_ptr[i] = excl; }
}

__global__ void scatter_k(const int* __restrict__ srcarr, const int* __restrict__ dstarr,
                          int* __restrict__ write_ptr, int* __restrict__ srcs) {
    int e = blockIdx.x * blockDim.x + threadIdx.x;
    if (e >= ETOT) return;
    int d, s;
    if (e < NE) { d = dstarr[e]; s = srcarr[e]; }
    else        { d = e - NE;    s = e - NE; }
    int pos = atomicAdd(&write_ptr[d], 1);
    srcs[pos] = s;
}

// ------------- wasd: per layer, was[k]=sum_c W[k][c]*as[c], wad likewise -------------

__global__ void wasd_k(const float* __restrict__ W, const float* __restrict__ asrc,
                       const float* __restrict__ adst, float* __restrict__ wasd) {
    int l = blockIdx.x;
    int t = threadIdx.x;
    int k = t & 127, which = t >> 7;
    const float* wr = W + (size_t)l * D * D + (size_t)k * D;
    const float* av = (which ? adst : asrc) + (size_t)l * D;
    float s = 0.f;
    #pragma unroll 4
    for (int c = 0; c < D; ++c) s += wr[c] * av[c];
    wasd[l * 256 + which * 128 + k] = s;
}

// ------------- xcvt: x -> fp16 table + layer-0 alphas (wave per row) -------------

__global__ __launch_bounds__(256) void xcvt_k(
        const float* __restrict__ x, const float* __restrict__ wasd0,
        __half* __restrict__ xh, float* __restrict__ alpha_s, float* __restrict__ alpha_d) {
    int n = (blockIdx.x * blockDim.x + threadIdx.x) >> 6;
    if (n >= NN) return;
    int lane = threadIdx.x & 63;
    float2 v = ((const float2*)(x + (size_t)n * D))[lane];
    ((__half2*)(xh + (size_t)n * D))[lane] = __floats2half2_rn(v.x, v.y);
    float ps = v.x * wasd0[2 * lane] + v.y * wasd0[2 * lane + 1];
    float pd = v.x * wasd0[128 + 2 * lane] + v.y * wasd0[128 + 2 * lane + 1];
    #pragma unroll
    for (int o = 32; o; o >>= 1) {
        ps += __shfl_xor(ps, o);
        pd += __shfl_xor(pd, o);
    }
    if (lane == 0) { alpha_s[n] = ps; alpha_d[n] = pd; }
}

// ------------- fused layer: gather fp16 h rows -> matvec W (LDS) -> out (+next alphas) ---
// 1024 threads = 16 waves; W (64KB fp32) staged once per block; wave per dst node x 2 reps.

template <int OUT_HALF, int HAS_NEXT, int GELU>
__global__ __launch_bounds__(1024) void fused_k(
        const int* __restrict__ row_ptr, const int* __restrict__ srcs,
        const float* __restrict__ alpha_s, const float* __restrict__ alpha_d,
        const __half* __restrict__ TH, const float* __restrict__ W,
        const float* __restrict__ bias, const float* __restrict__ wn,
        void* __restrict__ outp,
        float* __restrict__ alpha_s_nx, float* __restrict__ alpha_d_nx) {
    __shared__ float Ws[D * D];      // 64 KB
    int t = threadIdx.x;
    #pragma unroll
    for (int i = 0; i < 4; ++i)
        ((float4*)Ws)[t + i * 1024] = ((const float4*)W)[t + i * 1024];
    __syncthreads();

    int wid = t >> 6, lane = t & 63;
    const uint4* base = (const uint4*)TH;   // fp16 row = 16 uint4

    for (int rep = 0; rep < 2; ++rep) {
        int n = blockIdx.x * 32 + rep * 16 + wid;
        if (n >= NN) continue;
        int beg = row_ptr[n], end = row_ptr[n + 1], deg = end - beg;
        float ad = alpha_d[n];
        int qw = lane >> 4, q = lane & 15;
        float acc[8] = {0,0,0,0,0,0,0,0};
        float denom;

        if (deg <= 64) {
            int sreg = 0;
            float e = -3.4e38f;
            if (lane < deg) {
                sreg = srcs[beg + lane];
                float v = alpha_s[sreg] + ad;
                e = v > 0.f ? v : 0.2f * v;
            }
            float m = e;
            #pragma unroll
            for (int o = 32; o; o >>= 1) m = fmaxf(m, __shfl_xor(m, o));
            float w = (lane < deg) ? __expf(e - m) : 0.f;
            denom = w;
            #pragma unroll
            for (int o = 32; o; o >>= 1) denom += __shfl_xor(denom, o);

            int dgr = (deg + 3) & ~3;
            int j = 0;
            for (; j + 8 <= dgr; j += 8) {
                int e0 = j + qw, e1 = j + 4 + qw;
                int   s0 = __shfl(sreg, e0); float w0 = __shfl(w, e0);
                int   s1 = __shfl(sreg, e1); float w1 = __shfl(w, e1);
                uint4 u0 = base[(size_t)s0 * 16 + q];
                uint4 u1 = base[(size_t)s1 * 16 + q];
                {
                    union { uint4 u; __half2 h[4]; } U; U.u = u0;
                    float2 f0 = __half22float2(U.h[0]);
                    float2 f1 = __half22float2(U.h[1]);
                    float2 f2 = __half22float2(U.h[2]);
                    float2 f3 = __half22float2(U.h[3]);
                    acc[0] += w0*f0.x; acc[1] += w0*f0.y; acc[2] += w0*f1.x; acc[3] += w0*f1.y;
                    acc[4] += w0*f2.x; acc[5] += w0*f2.y; acc[6] += w0*f3.x; acc[7] += w0*f3.y;
                }
                {
                    union { uint4 u; __half2 h[4]; } U; U.u = u1;
                    float2 f0 = __half22float2(U.h[0]);
                    float2 f1 = __half22float2(U.h[1]);
                    float2 f2 = __half22float2(U.h[2]);
                    float2 f3 = __half22float2(U.h[3]);
                    acc[0] += w1*f0.x; acc[1] += w1*f0.y; acc[2] += w1*f1.x; acc[3] += w1*f1.y;
                    acc[4] += w1*f2.x; acc[5] += w1*f2.y; acc[6] += w1*f3.x; acc[7] += w1*f3.y;
                }
            }
            for (; j < dgr; j += 4) {
                int e0 = j + qw;
                int s0 = __shfl(sreg, e0); float w0 = __shfl(w, e0);
                uint4 u0 = base[(size_t)s0 * 16 + q];
                union { uint4 u; __half2 h[4]; } U; U.u = u0;
                float2 f0 = __half22float2(U.h[0]);
                float2 f1 = __half22float2(U.h[1]);
                float2 f2 = __half22float2(U.h[2]);
                float2 f3 = __half22float2(U.h[3]);
                acc[0] += w0*f0.x; acc[1] += w0*f0.y; acc[2] += w0*f1.x; acc[3] += w0*f1.y;
                acc[4] += w0*f2.x; acc[5] += w0*f2.y; acc[6] += w0*f3.x; acc[7] += w0*f3.y;
            }
        } else {
            // rare fallback: strided max/denom, then quarter-wave gather
            float m = -3.4e38f;
            for (int i = beg + lane; i < end; i += 64) {
                int s = srcs[i];
                float v = alpha_s[s] + ad; v = v > 0.f ? v : 0.2f * v;
                m = fmaxf(m, v);
            }
            #pragma unroll
            for (int o = 32; o; o >>= 1) m = fmaxf(m, __shfl_xor(m, o));
            denom = 0.f;
            for (int i = beg + lane; i < end; i += 64) {
                int s = srcs[i];
                float v = alpha_s[s] + ad; v = v > 0.f ? v : 0.2f * v;
                denom += __expf(v - m);
            }
            #pragma unroll
            for (int o = 32; o; o >>= 1) denom += __shfl_xor(denom, o);
            for (int j0 = beg; j0 < end; j0 += 4) {
                int idx = j0 + qw;
                int s0 = 0; float w0 = 0.f;
                if (idx < end) {
                    s0 = srcs[idx];
                    float v = alpha_s[s0] + ad; v = v > 0.f ? v : 0.2f * v;
                    w0 = __expf(v - m);
                }
                uint4 u0 = base[(size_t)s0 * 16 + q];
                union { uint4 u; __half2 h[4]; } U; U.u = u0;
                float2 f0 = __half22float2(U.h[0]);
                float2 f1 = __half22float2(U.h[1]);
                float2 f2 = __half22float2(U.h[2]);
                float2 f3 = __half22float2(U.h[3]);
                acc[0] += w0*f0.x; acc[1] += w0*f0.y; acc[2] += w0*f1.x; acc[3] += w0*f1.y;
                acc[4] += w0*f2.x; acc[5] += w0*f2.y; acc[6] += w0*f3.x; acc[7] += w0*f3.y;
            }
        }

        // reduce quarter-wave partials; normalize -> hv (lane kq holds feats 8*kq+f)
        #pragma unroll
        for (int f = 0; f < 8; ++f) {
            acc[f] += __shfl_xor(acc[f], 16);
            acc[f] += __shfl_xor(acc[f], 32);
        }
        float inv = 1.f / (denom + 1e-16f);
        float hv[8];
        #pragma unroll
        for (int f = 0; f < 8; ++f) hv[f] = acc[f] * inv;

        // matvec: out[c] for c in {lane, 64+lane}
        float ox = bias[lane], oy = bias[64 + lane];
        #pragma unroll
        for (int f = 0; f < 8; ++f) {
            float h0 = hv[f];
            #pragma unroll
            for (int kq = 0; kq < 16; ++kq) {
                float hk = rdlane(h0, kq);
                int k = kq * 8 + f;
                ox = fmaf(hk, Ws[k * D + lane], ox);
                oy = fmaf(hk, Ws[k * D + 64 + lane], oy);
            }
        }
        if (GELU) { ox = gelu_tanh(ox); oy = gelu_tanh(oy); }

        if (OUT_HALF) {
            __half* o = (__half*)outp + (size_t)n * D;
            o[lane]      = __float2half_rn(ox);
            o[64 + lane] = __float2half_rn(oy);
        } else {
            float* o = (float*)outp + (size_t)n * D;
            o[lane]      = ox;
            o[64 + lane] = oy;
        }

        if (HAS_NEXT) {
            float ps = ox * wn[lane] + oy * wn[64 + lane];
            float pd = ox * wn[128 + lane] + oy * wn[192 + lane];
            #pragma unroll
            for (int o2 = 32; o2; o2 >>= 1) {
                ps += __shfl_xor(ps, o2);
                pd += __shfl_xor(pd, o2);
            }
            if (lane == 0) { alpha_s_nx[n] = ps; alpha_d_nx[n] = pd; }
        }
    }
}

// ---------------- launch ----------------

extern "C" void kernel_launch(void* const* d_in, const int* in_sizes, int n_in,
                              void* d_out, int out_size, void* d_ws, size_t ws_size,
                              hipStream_t stream) {
    const float* x    = (const float*)d_in[0];
    const int*   ei   = (const int*)d_in[1];
    const float* W    = (const float*)d_in[2];
    const float* asrc = (const float*)d_in[3];
    const float* adst = (const float*)d_in[4];
    const float* bias = (const float*)d_in[5];
    float* out = (float*)d_out;

    const int* src_arr = ei;
    const int* dst_arr = ei + NE;

    char* ws = (char*)d_ws;
    size_t off = 0;
    auto alloc = [&](size_t bytes) { char* p = ws + off; off += (bytes + 255) & ~(size_t)255; return p; };
    __half* th_a    = (__half*)alloc((size_t)NN * D * sizeof(__half));
    __half* th_b    = (__half*)alloc((size_t)NN * D * sizeof(__half));
    float*  as_a    = (float*)alloc(NN * sizeof(float));
    float*  ad_a    = (float*)alloc(NN * sizeof(float));
    float*  as_b    = (float*)alloc(NN * sizeof(float));
    float*  ad_b    = (float*)alloc(NN * sizeof(float));
    float*  wasd    = (float*)alloc(3 * 256 * sizeof(float));
    int* counts    = (int*)alloc(NN * sizeof(int));
    int* row_ptr   = (int*)alloc((NN + 1) * sizeof(int));
    int* write_ptr = (int*)alloc(NN * sizeof(int));
    int* blk_sums  = (int*)alloc(NB * sizeof(int));
    int* blk_offs  = (int*)alloc(NB * sizeof(int));
    int* srcs      = (int*)alloc((size_t)ETOT * sizeof(int));
    (void)ws_size; (void)in_sizes; (void)n_in; (void)out_size;

    // CSR build (by dst), includes self loops
    hipMemsetAsync(counts, 0, NN * sizeof(int), stream);
    int eb = (ETOT + 255) / 256;
    count_k<<<eb, 256, 0, stream>>>(dst_arr, counts);
    scan1_k<<<NB, 256, 0, stream>>>(counts, blk_sums);
    scan2_k<<<1, 64, 0, stream>>>(blk_sums, blk_offs, row_ptr);
    scan3_k<<<NB, 256, 0, stream>>>(counts, blk_offs, row_ptr, write_ptr);
    scatter_k<<<eb, 256, 0, stream>>>(src_arr, dst_arr, write_ptr, srcs);

    // projected attention vectors for all layers
    wasd_k<<<3, 256, 0, stream>>>(W, asrc, adst, wasd);

    // layer-0 prep: fp16 table of x + alphas
    xcvt_k<<<NN / 4, 256, 0, stream>>>(x, wasd, th_a, as_a, ad_a);

    int fb = (NN + 31) / 32;   // 1563 blocks of 1024

    // layer 0: read th_a -> write th_b (+ layer-1 alphas)
    fused_k<1, 1, 1><<<fb, 1024, 0, stream>>>(row_ptr, srcs, as_a, ad_a, th_a,
                                              W, bias, wasd + 256,
                                              th_b, as_b, ad_b);
    // layer 1: read th_b -> write th_a (+ layer-2 alphas)
    fused_k<1, 1, 1><<<fb, 1024, 0, stream>>>(row_ptr, srcs, as_b, ad_b, th_b,
                                              W + (size_t)1 * D * D, bias + D, wasd + 512,
                                              th_a, as_a, ad_a);
    // layer 2: read th_a -> write fp32 out, no gelu, no next alphas
    fused_k<0, 0, 0><<<fb, 1024, 0, stream>>>(row_ptr, srcs, as_a, ad_a, th_a,
                                              W + (size_t)2 * D * D, bias + 2 * D, wasd,
                                              out, as_b, ad_b);
}

// Round 7
// 301.596 us; speedup vs baseline: 5.3121x; 5.3121x over previous
//
#include <hip/hip_runtime.h>
#include <hip/hip_bf16.h>
#include <hip/hip_fp16.h>

#define NN    50000
#define NE    800000
#define ETOT  (NE + NN)
#define D     128
#define NB    ((NN + 255) / 256)   // scan blocks

typedef _Float16 f16x8 __attribute__((ext_vector_type(8)));
typedef float    f32x4 __attribute__((ext_vector_type(4)));

__device__ __forceinline__ float gelu_tanh(float x) {
    float x3 = x * x * x;
    float t  = tanhf(0.7978845608028654f * (x + 0.044715f * x3));
    return 0.5f * x * (1.0f + t);
}

// ---------------- CSR build ----------------

__global__ void count_k(const int* __restrict__ dstarr, int* __restrict__ counts) {
    int e = blockIdx.x * blockDim.x + threadIdx.x;
    if (e >= ETOT) return;
    int d = (e < NE) ? dstarr[e] : (e - NE);
    atomicAdd(&counts[d], 1);
}

__global__ void scan1_k(const int* __restrict__ counts, int* __restrict__ blk_sums) {
    __shared__ int sm[4];
    int i = blockIdx.x * 256 + threadIdx.x;
    int v = (i < NN) ? counts[i] : 0;
    #pragma unroll
    for (int o = 32; o; o >>= 1) v += __shfl_xor(v, o);
    if ((threadIdx.x & 63) == 0) sm[threadIdx.x >> 6] = v;
    __syncthreads();
    if (threadIdx.x == 0) blk_sums[blockIdx.x] = sm[0] + sm[1] + sm[2] + sm[3];
}

__global__ void scan2_k(const int* __restrict__ blk_sums, int* __restrict__ blk_offs,
                        int* __restrict__ row_ptr) {
    if (threadIdx.x == 0 && blockIdx.x == 0) {
        int acc = 0;
        for (int b = 0; b < NB; ++b) { blk_offs[b] = acc; acc += blk_sums[b]; }
        row_ptr[NN] = acc;
    }
}

__global__ void scan3_k(const int* __restrict__ counts, const int* __restrict__ blk_offs,
                        int* __restrict__ row_ptr, int* __restrict__ write_ptr) {
    __shared__ int s[256];
    int t = threadIdx.x;
    int i = blockIdx.x * 256 + t;
    int v = (i < NN) ? counts[i] : 0;
    s[t] = v;
    __syncthreads();
    for (int off = 1; off < 256; off <<= 1) {
        int x = (t >= off) ? s[t - off] : 0;
        __syncthreads();
        s[t] += x;
        __syncthreads();
    }
    int excl = s[t] - v + blk_offs[blockIdx.x];
    if (i < NN) { row_ptr[i] = excl; write_ptr[i] = excl; }
}

__global__ void scatter_k(const int* __restrict__ srcarr, const int* __restrict__ dstarr,
                          int* __restrict__ write_ptr, int* __restrict__ srcs) {
    int e = blockIdx.x * blockDim.x + threadIdx.x;
    if (e >= ETOT) return;
    int d, s;
    if (e < NE) { d = dstarr[e]; s = srcarr[e]; }
    else        { d = e - NE;    s = e - NE; }
    int pos = atomicAdd(&write_ptr[d], 1);
    srcs[pos] = s;
}

// ------------- wasd: per layer, was[k]=sum_c W[k][c]*as[c], wad likewise -------------

__global__ void wasd_k(const float* __restrict__ W, const float* __restrict__ asrc,
                       const float* __restrict__ adst, float* __restrict__ wasd) {
    int l = blockIdx.x;
    int t = threadIdx.x;
    int k = t & 127, which = t >> 7;
    const float* wr = W + (size_t)l * D * D + (size_t)k * D;
    const float* av = (which ? adst : asrc) + (size_t)l * D;
    float s = 0.f;
    #pragma unroll 4
    for (int c = 0; c < D; ++c) s += wr[c] * av[c];
    wasd[l * 256 + which * 128 + k] = s;
}

// ------------- wt: W[l][k][c] fp32 -> WT[l][c][k] fp16 -------------

__global__ void wt_k(const float* __restrict__ W, __half* __restrict__ WT) {
    int l = blockIdx.y;
    int i = blockIdx.x * 256 + threadIdx.x;   // 0..16383
    int k = i >> 7, c = i & 127;
    WT[(size_t)l * 16384 + (size_t)c * 128 + k] =
        __float2half_rn(W[(size_t)l * 16384 + (size_t)k * 128 + c]);
}

// ------------- xcvt: x -> fp16 table + layer-0 alphas (wave per row) -------------

__global__ __launch_bounds__(256) void xcvt_k(
        const float* __restrict__ x, const float* __restrict__ wasd0,
        __half* __restrict__ xh, float* __restrict__ alpha_s, float* __restrict__ alpha_d) {
    int n = (blockIdx.x * blockDim.x + threadIdx.x) >> 6;
    if (n >= NN) return;
    int lane = threadIdx.x & 63;
    float2 v = ((const float2*)(x + (size_t)n * D))[lane];
    ((__half2*)(xh + (size_t)n * D))[lane] = __floats2half2_rn(v.x, v.y);
    float ps = v.x * wasd0[2 * lane] + v.y * wasd0[2 * lane + 1];
    float pd = v.x * wasd0[128 + 2 * lane] + v.y * wasd0[128 + 2 * lane + 1];
    #pragma unroll
    for (int o = 32; o; o >>= 1) {
        ps += __shfl_xor(ps, o);
        pd += __shfl_xor(pd, o);
    }
    if (lane == 0) { alpha_s[n] = ps; alpha_d[n] = pd; }
}

// ------------- MFMA fp16 GEMM: XP = TH @ W (WT fp16 [c][k], LDS-staged + swizzled) -----
// 256 thr = 4 waves; block tile 256 rows x 64 cols; wave tile 64 rows x 64 cols.
// grid: blockIdx = 2*rowtile + colhalf.

template <int OUT32>
__global__ __launch_bounds__(256) void gemm_mfma_k(
        const __half* __restrict__ TH, const __half* __restrict__ WT,
        void* __restrict__ XP) {
    __shared__ __half Bs[D * D];     // 32 KB, [c][k] with byte^((c&7)<<4) swizzle
    int t = threadIdx.x;
    #pragma unroll
    for (int it = 0; it < 8; ++it) {
        int b = it * 4096 + t * 16;                 // byte index into WT layer
        int c = b >> 8;
        int swz = b ^ ((c & 7) << 4);
        *(uint4*)((char*)Bs + swz) = *(const uint4*)((const char*)WT + b);
    }
    __syncthreads();

    int w = t >> 6, lane = t & 63;
    int r0 = (blockIdx.x >> 1) * 256 + w * 64;      // wave's 64 rows
    int c0 = (blockIdx.x & 1) * 64;                 // col half
    int lr = lane & 15, lg = lane >> 4;

    f32x4 acc[4][4];
    #pragma unroll
    for (int i = 0; i < 4; ++i)
        #pragma unroll
        for (int j = 0; j < 4; ++j)
            acc[i][j] = (f32x4){0.f, 0.f, 0.f, 0.f};

    const char* abase = (const char*)TH;
    #pragma unroll
    for (int ks = 0; ks < 4; ++ks) {
        f16x8 bf[4];
        #pragma unroll
        for (int ct = 0; ct < 4; ++ct) {
            int c  = c0 + ct * 16 + lr;
            int kb = ks * 64 + lg * 16;
            int addr = c * 256 + (kb ^ ((c & 7) << 4));
            bf[ct] = *(const f16x8*)((const char*)Bs + addr);
        }
        #pragma unroll
        for (int rt = 0; rt < 4; ++rt) {
            int row = r0 + rt * 16 + lr;
            int rc  = row < NN ? row : NN - 1;
            f16x8 af = *(const f16x8*)(abase + (size_t)rc * 256 + ks * 64 + lg * 16);
            #pragma unroll
            for (int ct = 0; ct < 4; ++ct)
                acc[rt][ct] = __builtin_amdgcn_mfma_f32_16x16x32_f16(
                                  af, bf[ct], acc[rt][ct], 0, 0, 0);
        }
    }

    // D mapping: col = lane&15, row = (lane>>4)*4 + q  [HW-verified, dtype-independent]
    #pragma unroll
    for (int rt = 0; rt < 4; ++rt) {
        #pragma unroll
        for (int q = 0; q < 4; ++q) {
            int row = r0 + rt * 16 + lg * 4 + q;
            if (row < NN) {
                #pragma unroll
                for (int ct = 0; ct < 4; ++ct) {
                    int col = c0 + ct * 16 + lr;
                    if (OUT32)
                        ((float*)XP)[(size_t)row * D + col] = acc[rt][ct][q];
                    else
                        ((__half*)XP)[(size_t)row * D + col] = __float2half_rn(acc[rt][ct][q]);
                }
            }
        }
    }
}

// ---------------- fp16 aggregation (layers 0,1): gather xp fp16, write h fp16 + next alphas --

__global__ __launch_bounds__(256) void agg_half2_k(
        const int* __restrict__ row_ptr, const int* __restrict__ srcs,
        const float* __restrict__ alpha_s, const float* __restrict__ alpha_d,
        const __half* __restrict__ XPH, const float* __restrict__ bias,
        const float* __restrict__ wn,
        __half* __restrict__ TH_OUT, float* __restrict__ as_nx, float* __restrict__ ad_nx) {
    int n = (blockIdx.x * blockDim.x + threadIdx.x) >> 6;
    int lane = threadIdx.x & 63;
    int beg = row_ptr[n], end = row_ptr[n + 1], deg = end - beg;
    float ad = alpha_d[n];
    int qw = lane >> 4, q = lane & 15;
    float rv[8] = {0,0,0,0,0,0,0,0};
    float ps = 0.f, pd = 0.f;

    if (deg <= 64) {
        int sreg = 0;
        float e = -3.4e38f;
        if (lane < deg) {
            sreg = srcs[beg + lane];
            float v = alpha_s[sreg] + ad;
            e = v > 0.f ? v : 0.2f * v;
        }
        float m = e;
        #pragma unroll
        for (int o = 32; o; o >>= 1) m = fmaxf(m, __shfl_xor(m, o));
        float w = (lane < deg) ? __expf(e - m) : 0.f;
        float denom = w;
        #pragma unroll
        for (int o = 32; o; o >>= 1) denom += __shfl_xor(denom, o);

        float acc[8] = {0,0,0,0,0,0,0,0};
        int dgr = (deg + 3) & ~3;
        const uint4* base = (const uint4*)XPH;
        int j = 0;
        #define GATHER1(JOFF, ACCUM)                                             \
            {                                                                    \
                int ee = j + (JOFF) + qw;                                        \
                int   ss = __shfl(sreg, ee); float ww = __shfl(w, ee);           \
                uint4 uu = base[(size_t)ss * 16 + q];                            \
                union { uint4 u; __half2 h[4]; } U; U.u = uu;                    \
                float2 f0 = __half22float2(U.h[0]);                              \
                float2 f1 = __half22float2(U.h[1]);                              \
                float2 f2 = __half22float2(U.h[2]);                              \
                float2 f3 = __half22float2(U.h[3]);                              \
                ACCUM[0] += ww*f0.x; ACCUM[1] += ww*f0.y;                        \
                ACCUM[2] += ww*f1.x; ACCUM[3] += ww*f1.y;                        \
                ACCUM[4] += ww*f2.x; ACCUM[5] += ww*f2.y;                        \
                ACCUM[6] += ww*f3.x; ACCUM[7] += ww*f3.y;                        \
            }
        for (; j + 16 <= dgr; j += 16) {
            GATHER1(0, acc) GATHER1(4, acc) GATHER1(8, acc) GATHER1(12, acc)
        }
        for (; j < dgr; j += 4) {
            GATHER1(0, acc)
        }
        #undef GATHER1
        #pragma unroll
        for (int f = 0; f < 8; ++f) {
            acc[f] += __shfl_xor(acc[f], 16);
            acc[f] += __shfl_xor(acc[f], 32);
        }
        float inv = 1.f / (denom + 1e-16f);
        const float4* b4 = (const float4*)bias;
        float4 ba = b4[q * 2], bb = b4[q * 2 + 1];
        rv[0] = gelu_tanh(acc[0]*inv + ba.x); rv[1] = gelu_tanh(acc[1]*inv + ba.y);
        rv[2] = gelu_tanh(acc[2]*inv + ba.z); rv[3] = gelu_tanh(acc[3]*inv + ba.w);
        rv[4] = gelu_tanh(acc[4]*inv + bb.x); rv[5] = gelu_tanh(acc[5]*inv + bb.y);
        rv[6] = gelu_tanh(acc[6]*inv + bb.z); rv[7] = gelu_tanh(acc[7]*inv + bb.w);

        if (lane < 16) {
            union { uint4 u; __half2 h[4]; } P;
            P.h[0] = __floats2half2_rn(rv[0], rv[1]);
            P.h[1] = __floats2half2_rn(rv[2], rv[3]);
            P.h[2] = __floats2half2_rn(rv[4], rv[5]);
            P.h[3] = __floats2half2_rn(rv[6], rv[7]);
            *(uint4*)(TH_OUT + (size_t)n * D + q * 8) = P.u;
        }
        if (lane < 16) {
            const float4* w4 = (const float4*)wn;
            float4 wa = w4[q * 2], wb = w4[q * 2 + 1];
            const float4* w4d = (const float4*)(wn + 128);
            float4 wda = w4d[q * 2], wdb = w4d[q * 2 + 1];
            ps = rv[0]*wa.x + rv[1]*wa.y + rv[2]*wa.z + rv[3]*wa.w
               + rv[4]*wb.x + rv[5]*wb.y + rv[6]*wb.z + rv[7]*wb.w;
            pd = rv[0]*wda.x + rv[1]*wda.y + rv[2]*wda.z + rv[3]*wda.w
               + rv[4]*wdb.x + rv[5]*wdb.y + rv[6]*wdb.z + rv[7]*wdb.w;
        }
        #pragma unroll
        for (int o = 8; o; o >>= 1) {
            ps += __shfl_xor(ps, o);
            pd += __shfl_xor(pd, o);
        }
        if (lane == 0) { as_nx[n] = ps; ad_nx[n] = pd; }
    } else {
        // rare fallback (deg > 64): 3-pass, 2 features per lane
        float m = -3.4e38f;
        for (int i = beg + lane; i < end; i += 64) {
            int s = srcs[i];
            float v = alpha_s[s] + ad; v = v > 0.f ? v : 0.2f * v;
            m = fmaxf(m, v);
        }
        #pragma unroll
        for (int o = 32; o; o >>= 1) m = fmaxf(m, __shfl_xor(m, o));
        float denom = 0.f;
        for (int i = beg + lane; i < end; i += 64) {
            int s = srcs[i];
            float v = alpha_s[s] + ad; v = v > 0.f ? v : 0.2f * v;
            denom += __expf(v - m);
        }
        #pragma unroll
        for (int o = 32; o; o >>= 1) denom += __shfl_xor(denom, o);
        float2 acc = {0.f, 0.f};
        for (int i = beg; i < end; ++i) {
            int s = srcs[i];
            float v = alpha_s[s] + ad; v = v > 0.f ? v : 0.2f * v;
            float wgt = __expf(v - m);
            union { unsigned int x; __half2 h; } U;
            U.x = ((const unsigned int*)(XPH + (size_t)s * D))[lane];
            float2 f = __half22float2(U.h);
            acc.x += wgt * f.x; acc.y += wgt * f.y;
        }
        float inv = 1.f / (denom + 1e-16f);
        float2 b2 = ((const float2*)bias)[lane];
        float r0 = gelu_tanh(acc.x * inv + b2.x);
        float r1 = gelu_tanh(acc.y * inv + b2.y);
        ((__half2*)(TH_OUT + (size_t)n * D))[lane] = __floats2half2_rn(r0, r1);
        float psf = r0 * wn[2 * lane] + r1 * wn[2 * lane + 1];
        float pdf = r0 * wn[128 + 2 * lane] + r1 * wn[128 + 2 * lane + 1];
        #pragma unroll
        for (int o = 32; o; o >>= 1) {
            psf += __shfl_xor(psf, o);
            pdf += __shfl_xor(pdf, o);
        }
        if (lane == 0) { as_nx[n] = psf; ad_nx[n] = pdf; }
    }
}

// ---------------- fp32 aggregation (layer 3) — proven R3/R4 code ----------------

__global__ __launch_bounds__(256) void agg_k(
        const int* __restrict__ row_ptr, const int* __restrict__ srcs,
        const float* __restrict__ alpha_s, const float* __restrict__ alpha_d,
        const float* __restrict__ XP, const float* __restrict__ bias,
        float* __restrict__ OUT, int apply_gelu) {
    int n = (blockIdx.x * blockDim.x + threadIdx.x) >> 6;
    int lane = threadIdx.x & 63;
    int beg = row_ptr[n], end = row_ptr[n + 1], deg = end - beg;
    float ad = alpha_d[n];

    if (deg <= 64) {
        int sreg = 0;
        float e = -3.4e38f;
        if (lane < deg) {
            sreg = srcs[beg + lane];
            float v = alpha_s[sreg] + ad;
            e = v > 0.f ? v : 0.2f * v;
        }
        float m = e;
        #pragma unroll
        for (int o = 32; o; o >>= 1) m = fmaxf(m, __shfl_xor(m, o));
        float w = (lane < deg) ? __expf(e - m) : 0.f;
        float denom = w;
        #pragma unroll
        for (int o = 32; o; o >>= 1) denom += __shfl_xor(denom, o);

        int half = lane >> 5, q = lane & 31;
        float4 acc0 = {0,0,0,0}, acc1 = {0,0,0,0};
        int j = 0;
        for (; j + 4 <= deg; j += 4) {
            int   s0 = __shfl(sreg, j + half);
            float w0 = __shfl(w,    j + half);
            int   s1 = __shfl(sreg, j + 2 + half);
            float w1 = __shfl(w,    j + 2 + half);
            float4 x0 = ((const float4*)(XP + (size_t)s0 * D))[q];
            float4 x1 = ((const float4*)(XP + (size_t)s1 * D))[q];
            acc0.x += w0 * x0.x; acc0.y += w0 * x0.y;
            acc0.z += w0 * x0.z; acc0.w += w0 * x0.w;
            acc1.x += w1 * x1.x; acc1.y += w1 * x1.y;
            acc1.z += w1 * x1.z; acc1.w += w1 * x1.w;
        }
        for (; j < deg; j += 2) {
            int ej = j + half;
            int   s0 = __shfl(sreg, ej < 63 ? ej : 63);
            float w0 = __shfl(w,    ej < 63 ? ej : 63);
            if (ej < deg) {
                float4 x0 = ((const float4*)(XP + (size_t)s0 * D))[q];
                acc0.x += w0 * x0.x; acc0.y += w0 * x0.y;
                acc0.z += w0 * x0.z; acc0.w += w0 * x0.w;
            }
        }
        float4 tot;
        tot.x = acc0.x + acc1.x; tot.y = acc0.y + acc1.y;
        tot.z = acc0.z + acc1.z; tot.w = acc0.w + acc1.w;
        tot.x += __shfl_xor(tot.x, 32);
        tot.y += __shfl_xor(tot.y, 32);
        tot.z += __shfl_xor(tot.z, 32);
        tot.w += __shfl_xor(tot.w, 32);

        if (half == 0) {
            float inv = 1.f / (denom + 1e-16f);
            float4 b4 = ((const float4*)bias)[q];
            float r0 = tot.x * inv + b4.x;
            float r1 = tot.y * inv + b4.y;
            float r2 = tot.z * inv + b4.z;
            float r3 = tot.w * inv + b4.w;
            if (apply_gelu) {
                r0 = gelu_tanh(r0); r1 = gelu_tanh(r1);
                r2 = gelu_tanh(r2); r3 = gelu_tanh(r3);
            }
            ((float4*)(OUT + (size_t)n * D))[q] = make_float4(r0, r1, r2, r3);
        }
    } else {
        float m = -3.4e38f;
        for (int i = beg + lane; i < end; i += 64) {
            int s = srcs[i];
            float v = alpha_s[s] + ad;
            v = v > 0.f ? v : 0.2f * v;
            m = fmaxf(m, v);
        }
        #pragma unroll
        for (int o = 32; o; o >>= 1) m = fmaxf(m, __shfl_xor(m, o));
        float denom = 0.f;
        for (int i = beg + lane; i < end; i += 64) {
            int s = srcs[i];
            float v = alpha_s[s] + ad;
            v = v > 0.f ? v : 0.2f * v;
            denom += __expf(v - m);
        }
        #pragma unroll
        for (int o = 32; o; o >>= 1) denom += __shfl_xor(denom, o);
        float2 acc = {0.f, 0.f};
        for (int i = beg; i < end; ++i) {
            int s = srcs[i];
            float v = alpha_s[s] + ad;
            v = v > 0.f ? v : 0.2f * v;
            float wgt = __expf(v - m);
            float2 xv = ((const float2*)(XP + (size_t)s * D))[lane];
            acc.x += wgt * xv.x;
            acc.y += wgt * xv.y;
        }
        float inv = 1.f / (denom + 1e-16f);
        float2 b2 = ((const float2*)bias)[lane];
        float r0 = acc.x * inv + b2.x;
        float r1 = acc.y * inv + b2.y;
        if (apply_gelu) { r0 = gelu_tanh(r0); r1 = gelu_tanh(r1); }
        ((float2*)(OUT + (size_t)n * D))[lane] = make_float2(r0, r1);
    }
}

// ---------------- launch ----------------

extern "C" void kernel_launch(void* const* d_in, const int* in_sizes, int n_in,
                              void* d_out, int out_size, void* d_ws, size_t ws_size,
                              hipStream_t stream) {
    const float* x    = (const float*)d_in[0];
    const int*   ei   = (const int*)d_in[1];
    const float* W    = (const float*)d_in[2];
    const float* asrc = (const float*)d_in[3];
    const float* adst = (const float*)d_in[4];
    const float* bias = (const float*)d_in[5];
    float* out = (float*)d_out;

    const int* src_arr = ei;
    const int* dst_arr = ei + NE;

    char* ws = (char*)d_ws;
    size_t off = 0;
    auto alloc = [&](size_t bytes) { char* p = ws + off; off += (bytes + 255) & ~(size_t)255; return p; };
    __half* th_a    = (__half*)alloc((size_t)NN * D * sizeof(__half));
    __half* th_b    = (__half*)alloc((size_t)NN * D * sizeof(__half));
    __half* xph     = (__half*)alloc((size_t)NN * D * sizeof(__half));
    float*  xp      = (float*)alloc((size_t)NN * D * sizeof(float));
    __half* wt      = (__half*)alloc((size_t)3 * D * D * sizeof(__half));
    float*  as_a    = (float*)alloc(NN * sizeof(float));
    float*  ad_a    = (float*)alloc(NN * sizeof(float));
    float*  as_b    = (float*)alloc(NN * sizeof(float));
    float*  ad_b    = (float*)alloc(NN * sizeof(float));
    float*  wasd    = (float*)alloc(3 * 256 * sizeof(float));
    int* counts    = (int*)alloc(NN * sizeof(int));
    int* row_ptr   = (int*)alloc((NN + 1) * sizeof(int));
    int* write_ptr = (int*)alloc(NN * sizeof(int));
    int* blk_sums  = (int*)alloc(NB * sizeof(int));
    int* blk_offs  = (int*)alloc(NB * sizeof(int));
    int* srcs      = (int*)alloc((size_t)ETOT * sizeof(int));
    (void)ws_size; (void)in_sizes; (void)n_in; (void)out_size;

    // CSR build (by dst), includes self loops
    hipMemsetAsync(counts, 0, NN * sizeof(int), stream);
    int eb = (ETOT + 255) / 256;
    count_k<<<eb, 256, 0, stream>>>(dst_arr, counts);
    scan1_k<<<NB, 256, 0, stream>>>(counts, blk_sums);
    scan2_k<<<1, 64, 0, stream>>>(blk_sums, blk_offs, row_ptr);
    scan3_k<<<NB, 256, 0, stream>>>(counts, blk_offs, row_ptr, write_ptr);
    scatter_k<<<eb, 256, 0, stream>>>(src_arr, dst_arr, write_ptr, srcs);

    // prep: projected attention vectors, W^T fp16, x fp16 + layer-0 alphas
    wasd_k<<<3, 256, 0, stream>>>(W, asrc, adst, wasd);
    wt_k<<<dim3(64, 3), 256, 0, stream>>>(W, wt);
    xcvt_k<<<NN / 4, 256, 0, stream>>>(x, wasd, th_a, as_a, ad_a);

    int gb = 2 * ((NN + 255) / 256);   // 392
    int ab = NN / 4;                   // 12500

    // layer 0
    gemm_mfma_k<0><<<gb, 256, 0, stream>>>(th_a, wt, xph);
    agg_half2_k<<<ab, 256, 0, stream>>>(row_ptr, srcs, as_a, ad_a, xph,
                                        bias, wasd + 256, th_b, as_b, ad_b);
    // layer 1
    gemm_mfma_k<0><<<gb, 256, 0, stream>>>(th_b, wt + 16384, xph);
    agg_half2_k<<<ab, 256, 0, stream>>>(row_ptr, srcs, as_b, ad_b, xph,
                                        bias + D, wasd + 512, th_a, as_a, ad_a);
    // layer 2: fp32 xp, fp32 out, no gelu
    gemm_mfma_k<1><<<gb, 256, 0, stream>>>(th_a, wt + 32768, xp);
    agg_k<<<ab, 256, 0, stream>>>(row_ptr, srcs, as_a, ad_a, xp,
                                  bias + 2 * D, out, 0);
}

// Round 8
// 259.380 us; speedup vs baseline: 6.1766x; 1.1628x over previous
//
#include <hip/hip_runtime.h>
#include <hip/hip_bf16.h>
#include <hip/hip_fp16.h>

#define NN    50000
#define NE    800000
#define ETOT  (NE + NN)
#define D     128
#define NB    ((NN + 255) / 256)   // scan blocks

typedef _Float16 f16x8 __attribute__((ext_vector_type(8)));
typedef float    f32x4 __attribute__((ext_vector_type(4)));

__device__ __forceinline__ float gelu_tanh(float x) {
    float x3 = x * x * x;
    float t  = tanhf(0.7978845608028654f * (x + 0.044715f * x3));
    return 0.5f * x * (1.0f + t);
}

// ---------------- CSR build ----------------

// count + rank: rank[e] = this edge's arrival index within its dst row
__global__ void count_k(const int* __restrict__ dstarr, int* __restrict__ counts,
                        int* __restrict__ rank) {
    int e = blockIdx.x * blockDim.x + threadIdx.x;
    if (e >= ETOT) return;
    int d = (e < NE) ? dstarr[e] : (e - NE);
    rank[e] = atomicAdd(&counts[d], 1);
}

__global__ void scan1_k(const int* __restrict__ counts, int* __restrict__ blk_sums) {
    __shared__ int sm[4];
    int i = blockIdx.x * 256 + threadIdx.x;
    int v = (i < NN) ? counts[i] : 0;
    #pragma unroll
    for (int o = 32; o; o >>= 1) v += __shfl_xor(v, o);
    if ((threadIdx.x & 63) == 0) sm[threadIdx.x >> 6] = v;
    __syncthreads();
    if (threadIdx.x == 0) blk_sums[blockIdx.x] = sm[0] + sm[1] + sm[2] + sm[3];
}

__global__ void scan2_k(const int* __restrict__ blk_sums, int* __restrict__ blk_offs,
                        int* __restrict__ row_ptr) {
    if (threadIdx.x == 0 && blockIdx.x == 0) {
        int acc = 0;
        for (int b = 0; b < NB; ++b) { blk_offs[b] = acc; acc += blk_sums[b]; }
        row_ptr[NN] = acc;
    }
}

__global__ void scan3_k(const int* __restrict__ counts, const int* __restrict__ blk_offs,
                        int* __restrict__ row_ptr) {
    __shared__ int s[256];
    int t = threadIdx.x;
    int i = blockIdx.x * 256 + t;
    int v = (i < NN) ? counts[i] : 0;
    s[t] = v;
    __syncthreads();
    for (int off = 1; off < 256; off <<= 1) {
        int x = (t >= off) ? s[t - off] : 0;
        __syncthreads();
        s[t] += x;
        __syncthreads();
    }
    int excl = s[t] - v + blk_offs[blockIdx.x];
    if (i < NN) row_ptr[i] = excl;
}

// atomic-free scatter: pos = row_ptr[dst] + rank
__global__ void scatter2_k(const int* __restrict__ srcarr, const int* __restrict__ dstarr,
                           const int* __restrict__ rank, const int* __restrict__ row_ptr,
                           int* __restrict__ srcs) {
    int e = blockIdx.x * blockDim.x + threadIdx.x;
    if (e >= ETOT) return;
    int d, s;
    if (e < NE) { d = dstarr[e]; s = srcarr[e]; }
    else        { d = e - NE;    s = e - NE; }
    srcs[row_ptr[d] + rank[e]] = s;
}

// ------------- wasd: per layer, was[k]=sum_c W[k][c]*as[c], wad likewise -------------

__global__ void wasd_k(const float* __restrict__ W, const float* __restrict__ asrc,
                       const float* __restrict__ adst, float* __restrict__ wasd) {
    int l = blockIdx.x;
    int t = threadIdx.x;
    int k = t & 127, which = t >> 7;
    const float* wr = W + (size_t)l * D * D + (size_t)k * D;
    const float* av = (which ? adst : asrc) + (size_t)l * D;
    float s = 0.f;
    #pragma unroll 4
    for (int c = 0; c < D; ++c) s += wr[c] * av[c];
    wasd[l * 256 + which * 128 + k] = s;
}

// ------------- wt: W[l][k][c] fp32 -> WT[l][c][k] fp16 -------------

__global__ void wt_k(const float* __restrict__ W, __half* __restrict__ WT) {
    int l = blockIdx.y;
    int i = blockIdx.x * 256 + threadIdx.x;   // 0..16383
    int k = i >> 7, c = i & 127;
    WT[(size_t)l * 16384 + (size_t)c * 128 + k] =
        __float2half_rn(W[(size_t)l * 16384 + (size_t)k * 128 + c]);
}

// ------------- xcvt: x -> fp16 table + layer-0 alphas (wave per row) -------------

__global__ __launch_bounds__(256) void xcvt_k(
        const float* __restrict__ x, const float* __restrict__ wasd0,
        __half* __restrict__ xh, float* __restrict__ alpha_s, float* __restrict__ alpha_d) {
    int n = (blockIdx.x * blockDim.x + threadIdx.x) >> 6;
    if (n >= NN) return;
    int lane = threadIdx.x & 63;
    float2 v = ((const float2*)(x + (size_t)n * D))[lane];
    ((__half2*)(xh + (size_t)n * D))[lane] = __floats2half2_rn(v.x, v.y);
    float ps = v.x * wasd0[2 * lane] + v.y * wasd0[2 * lane + 1];
    float pd = v.x * wasd0[128 + 2 * lane] + v.y * wasd0[128 + 2 * lane + 1];
    #pragma unroll
    for (int o = 32; o; o >>= 1) {
        ps += __shfl_xor(ps, o);
        pd += __shfl_xor(pd, o);
    }
    if (lane == 0) { alpha_s[n] = ps; alpha_d[n] = pd; }
}

// ------------- MFMA fp16 GEMM: XP = TH @ W (WT fp16 [c][k], LDS-staged + swizzled) -----

template <int OUT32>
__global__ __launch_bounds__(256) void gemm_mfma_k(
        const __half* __restrict__ TH, const __half* __restrict__ WT,
        void* __restrict__ XP) {
    __shared__ __half Bs[D * D];     // 32 KB, [c][k] with byte^((c&7)<<4) swizzle
    int t = threadIdx.x;
    #pragma unroll
    for (int it = 0; it < 8; ++it) {
        int b = it * 4096 + t * 16;
        int c = b >> 8;
        int swz = b ^ ((c & 7) << 4);
        *(uint4*)((char*)Bs + swz) = *(const uint4*)((const char*)WT + b);
    }
    __syncthreads();

    int w = t >> 6, lane = t & 63;
    int r0 = (blockIdx.x >> 1) * 256 + w * 64;
    int c0 = (blockIdx.x & 1) * 64;
    int lr = lane & 15, lg = lane >> 4;

    f32x4 acc[4][4];
    #pragma unroll
    for (int i = 0; i < 4; ++i)
        #pragma unroll
        for (int j = 0; j < 4; ++j)
            acc[i][j] = (f32x4){0.f, 0.f, 0.f, 0.f};

    const char* abase = (const char*)TH;
    #pragma unroll
    for (int ks = 0; ks < 4; ++ks) {
        f16x8 bf[4];
        #pragma unroll
        for (int ct = 0; ct < 4; ++ct) {
            int c  = c0 + ct * 16 + lr;
            int kb = ks * 64 + lg * 16;
            int addr = c * 256 + (kb ^ ((c & 7) << 4));
            bf[ct] = *(const f16x8*)((const char*)Bs + addr);
        }
        #pragma unroll
        for (int rt = 0; rt < 4; ++rt) {
            int row = r0 + rt * 16 + lr;
            int rc  = row < NN ? row : NN - 1;
            f16x8 af = *(const f16x8*)(abase + (size_t)rc * 256 + ks * 64 + lg * 16);
            #pragma unroll
            for (int ct = 0; ct < 4; ++ct)
                acc[rt][ct] = __builtin_amdgcn_mfma_f32_16x16x32_f16(
                                  af, bf[ct], acc[rt][ct], 0, 0, 0);
        }
    }

    #pragma unroll
    for (int rt = 0; rt < 4; ++rt) {
        #pragma unroll
        for (int q = 0; q < 4; ++q) {
            int row = r0 + rt * 16 + lg * 4 + q;
            if (row < NN) {
                #pragma unroll
                for (int ct = 0; ct < 4; ++ct) {
                    int col = c0 + ct * 16 + lr;
                    if (OUT32)
                        ((float*)XP)[(size_t)row * D + col] = acc[rt][ct][q];
                    else
                        ((__half*)XP)[(size_t)row * D + col] = __float2half_rn(acc[rt][ct][q]);
                }
            }
        }
    }
}

// ---------------- fp16 aggregation (layers 0,1): gather xp fp16, write h fp16 + next alphas --

__global__ __launch_bounds__(256) void agg_half2_k(
        const int* __restrict__ row_ptr, const int* __restrict__ srcs,
        const float* __restrict__ alpha_s, const float* __restrict__ alpha_d,
        const __half* __restrict__ XPH, const float* __restrict__ bias,
        const float* __restrict__ wn,
        __half* __restrict__ TH_OUT, float* __restrict__ as_nx, float* __restrict__ ad_nx) {
    int n = (blockIdx.x * blockDim.x + threadIdx.x) >> 6;
    int lane = threadIdx.x & 63;
    int beg = row_ptr[n], end = row_ptr[n + 1], deg = end - beg;
    float ad = alpha_d[n];
    int qw = lane >> 4, q = lane & 15;
    float rv[8] = {0,0,0,0,0,0,0,0};
    float ps = 0.f, pd = 0.f;

    if (deg <= 64) {
        int sreg = 0;
        float e = -3.4e38f;
        if (lane < deg) {
            sreg = srcs[beg + lane];
            float v = alpha_s[sreg] + ad;
            e = v > 0.f ? v : 0.2f * v;
        }
        float m = e;
        #pragma unroll
        for (int o = 32; o; o >>= 1) m = fmaxf(m, __shfl_xor(m, o));
        float w = (lane < deg) ? __expf(e - m) : 0.f;
        float denom = w;
        #pragma unroll
        for (int o = 32; o; o >>= 1) denom += __shfl_xor(denom, o);

        float acc[8] = {0,0,0,0,0,0,0,0};
        int dgr = (deg + 3) & ~3;
        const uint4* base = (const uint4*)XPH;
        int j = 0;
        #define GATHER1(JOFF, ACCUM)                                             \
            {                                                                    \
                int ee = j + (JOFF) + qw;                                        \
                int   ss = __shfl(sreg, ee); float ww = __shfl(w, ee);           \
                uint4 uu = base[(size_t)ss * 16 + q];                            \
                union { uint4 u; __half2 h[4]; } U; U.u = uu;                    \
                float2 f0 = __half22float2(U.h[0]);                              \
                float2 f1 = __half22float2(U.h[1]);                              \
                float2 f2 = __half22float2(U.h[2]);                              \
                float2 f3 = __half22float2(U.h[3]);                              \
                ACCUM[0] += ww*f0.x; ACCUM[1] += ww*f0.y;                        \
                ACCUM[2] += ww*f1.x; ACCUM[3] += ww*f1.y;                        \
                ACCUM[4] += ww*f2.x; ACCUM[5] += ww*f2.y;                        \
                ACCUM[6] += ww*f3.x; ACCUM[7] += ww*f3.y;                        \
            }
        for (; j + 16 <= dgr; j += 16) {
            GATHER1(0, acc) GATHER1(4, acc) GATHER1(8, acc) GATHER1(12, acc)
        }
        for (; j < dgr; j += 4) {
            GATHER1(0, acc)
        }
        #undef GATHER1
        #pragma unroll
        for (int f = 0; f < 8; ++f) {
            acc[f] += __shfl_xor(acc[f], 16);
            acc[f] += __shfl_xor(acc[f], 32);
        }
        float inv = 1.f / (denom + 1e-16f);
        const float4* b4 = (const float4*)bias;
        float4 ba = b4[q * 2], bb = b4[q * 2 + 1];
        rv[0] = gelu_tanh(acc[0]*inv + ba.x); rv[1] = gelu_tanh(acc[1]*inv + ba.y);
        rv[2] = gelu_tanh(acc[2]*inv + ba.z); rv[3] = gelu_tanh(acc[3]*inv + ba.w);
        rv[4] = gelu_tanh(acc[4]*inv + bb.x); rv[5] = gelu_tanh(acc[5]*inv + bb.y);
        rv[6] = gelu_tanh(acc[6]*inv + bb.z); rv[7] = gelu_tanh(acc[7]*inv + bb.w);

        if (lane < 16) {
            union { uint4 u; __half2 h[4]; } P;
            P.h[0] = __floats2half2_rn(rv[0], rv[1]);
            P.h[1] = __floats2half2_rn(rv[2], rv[3]);
            P.h[2] = __floats2half2_rn(rv[4], rv[5]);
            P.h[3] = __floats2half2_rn(rv[6], rv[7]);
            *(uint4*)(TH_OUT + (size_t)n * D + q * 8) = P.u;
        }
        if (lane < 16) {
            const float4* w4 = (const float4*)wn;
            float4 wa = w4[q * 2], wb = w4[q * 2 + 1];
            const float4* w4d = (const float4*)(wn + 128);
            float4 wda = w4d[q * 2], wdb = w4d[q * 2 + 1];
            ps = rv[0]*wa.x + rv[1]*wa.y + rv[2]*wa.z + rv[3]*wa.w
               + rv[4]*wb.x + rv[5]*wb.y + rv[6]*wb.z + rv[7]*wb.w;
            pd = rv[0]*wda.x + rv[1]*wda.y + rv[2]*wda.z + rv[3]*wda.w
               + rv[4]*wdb.x + rv[5]*wdb.y + rv[6]*wdb.z + rv[7]*wdb.w;
        }
        #pragma unroll
        for (int o = 8; o; o >>= 1) {
            ps += __shfl_xor(ps, o);
            pd += __shfl_xor(pd, o);
        }
        if (lane == 0) { as_nx[n] = ps; ad_nx[n] = pd; }
    } else {
        float m = -3.4e38f;
        for (int i = beg + lane; i < end; i += 64) {
            int s = srcs[i];
            float v = alpha_s[s] + ad; v = v > 0.f ? v : 0.2f * v;
            m = fmaxf(m, v);
        }
        #pragma unroll
        for (int o = 32; o; o >>= 1) m = fmaxf(m, __shfl_xor(m, o));
        float denom = 0.f;
        for (int i = beg + lane; i < end; i += 64) {
            int s = srcs[i];
            float v = alpha_s[s] + ad; v = v > 0.f ? v : 0.2f * v;
            denom += __expf(v - m);
        }
        #pragma unroll
        for (int o = 32; o; o >>= 1) denom += __shfl_xor(denom, o);
        float2 acc = {0.f, 0.f};
        for (int i = beg; i < end; ++i) {
            int s = srcs[i];
            float v = alpha_s[s] + ad; v = v > 0.f ? v : 0.2f * v;
            float wgt = __expf(v - m);
            union { unsigned int x; __half2 h; } U;
            U.x = ((const unsigned int*)(XPH + (size_t)s * D))[lane];
            float2 f = __half22float2(U.h);
            acc.x += wgt * f.x; acc.y += wgt * f.y;
        }
        float inv = 1.f / (denom + 1e-16f);
        float2 b2 = ((const float2*)bias)[lane];
        float r0 = gelu_tanh(acc.x * inv + b2.x);
        float r1 = gelu_tanh(acc.y * inv + b2.y);
        ((__half2*)(TH_OUT + (size_t)n * D))[lane] = __floats2half2_rn(r0, r1);
        float psf = r0 * wn[2 * lane] + r1 * wn[2 * lane + 1];
        float pdf = r0 * wn[128 + 2 * lane] + r1 * wn[128 + 2 * lane + 1];
        #pragma unroll
        for (int o = 32; o; o >>= 1) {
            psf += __shfl_xor(psf, o);
            pdf += __shfl_xor(pdf, o);
        }
        if (lane == 0) { as_nx[n] = psf; ad_nx[n] = pdf; }
    }
}

// ---------------- fp32 aggregation (layer 3) ----------------

__global__ __launch_bounds__(256) void agg_k(
        const int* __restrict__ row_ptr, const int* __restrict__ srcs,
        const float* __restrict__ alpha_s, const float* __restrict__ alpha_d,
        const float* __restrict__ XP, const float* __restrict__ bias,
        float* __restrict__ OUT, int apply_gelu) {
    int n = (blockIdx.x * blockDim.x + threadIdx.x) >> 6;
    int lane = threadIdx.x & 63;
    int beg = row_ptr[n], end = row_ptr[n + 1], deg = end - beg;
    float ad = alpha_d[n];

    if (deg <= 64) {
        int sreg = 0;
        float e = -3.4e38f;
        if (lane < deg) {
            sreg = srcs[beg + lane];
            float v = alpha_s[sreg] + ad;
            e = v > 0.f ? v : 0.2f * v;
        }
        float m = e;
        #pragma unroll
        for (int o = 32; o; o >>= 1) m = fmaxf(m, __shfl_xor(m, o));
        float w = (lane < deg) ? __expf(e - m) : 0.f;
        float denom = w;
        #pragma unroll
        for (int o = 32; o; o >>= 1) denom += __shfl_xor(denom, o);

        int half = lane >> 5, q = lane & 31;
        float4 acc0 = {0,0,0,0}, acc1 = {0,0,0,0};
        int j = 0;
        for (; j + 4 <= deg; j += 4) {
            int   s0 = __shfl(sreg, j + half);
            float w0 = __shfl(w,    j + half);
            int   s1 = __shfl(sreg, j + 2 + half);
            float w1 = __shfl(w,    j + 2 + half);
            float4 x0 = ((const float4*)(XP + (size_t)s0 * D))[q];
            float4 x1 = ((const float4*)(XP + (size_t)s1 * D))[q];
            acc0.x += w0 * x0.x; acc0.y += w0 * x0.y;
            acc0.z += w0 * x0.z; acc0.w += w0 * x0.w;
            acc1.x += w1 * x1.x; acc1.y += w1 * x1.y;
            acc1.z += w1 * x1.z; acc1.w += w1 * x1.w;
        }
        for (; j < deg; j += 2) {
            int ej = j + half;
            int   s0 = __shfl(sreg, ej < 63 ? ej : 63);
            float w0 = __shfl(w,    ej < 63 ? ej : 63);
            if (ej < deg) {
                float4 x0 = ((const float4*)(XP + (size_t)s0 * D))[q];
                acc0.x += w0 * x0.x; acc0.y += w0 * x0.y;
                acc0.z += w0 * x0.z; acc0.w += w0 * x0.w;
            }
        }
        float4 tot;
        tot.x = acc0.x + acc1.x; tot.y = acc0.y + acc1.y;
        tot.z = acc0.z + acc1.z; tot.w = acc0.w + acc1.w;
        tot.x += __shfl_xor(tot.x, 32);
        tot.y += __shfl_xor(tot.y, 32);
        tot.z += __shfl_xor(tot.z, 32);
        tot.w += __shfl_xor(tot.w, 32);

        if (half == 0) {
            float inv = 1.f / (denom + 1e-16f);
            float4 b4 = ((const float4*)bias)[q];
            float r0 = tot.x * inv + b4.x;
            float r1 = tot.y * inv + b4.y;
            float r2 = tot.z * inv + b4.z;
            float r3 = tot.w * inv + b4.w;
            if (apply_gelu) {
                r0 = gelu_tanh(r0); r1 = gelu_tanh(r1);
                r2 = gelu_tanh(r2); r3 = gelu_tanh(r3);
            }
            ((float4*)(OUT + (size_t)n * D))[q] = make_float4(r0, r1, r2, r3);
        }
    } else {
        float m = -3.4e38f;
        for (int i = beg + lane; i < end; i += 64) {
            int s = srcs[i];
            float v = alpha_s[s] + ad;
            v = v > 0.f ? v : 0.2f * v;
            m = fmaxf(m, v);
        }
        #pragma unroll
        for (int o = 32; o; o >>= 1) m = fmaxf(m, __shfl_xor(m, o));
        float denom = 0.f;
        for (int i = beg + lane; i < end; i += 64) {
            int s = srcs[i];
            float v = alpha_s[s] + ad;
            v = v > 0.f ? v : 0.2f * v;
            denom += __expf(v - m);
        }
        #pragma unroll
        for (int o = 32; o; o >>= 1) denom += __shfl_xor(denom, o);
        float2 acc = {0.f, 0.f};
        for (int i = beg; i < end; ++i) {
            int s = srcs[i];
            float v = alpha_s[s] + ad;
            v = v > 0.f ? v : 0.2f * v;
            float wgt = __expf(v - m);
            float2 xv = ((const float2*)(XP + (size_t)s * D))[lane];
            acc.x += wgt * xv.x;
            acc.y += wgt * xv.y;
        }
        float inv = 1.f / (denom + 1e-16f);
        float2 b2 = ((const float2*)bias)[lane];
        float r0 = acc.x * inv + b2.x;
        float r1 = acc.y * inv + b2.y;
        if (apply_gelu) { r0 = gelu_tanh(r0); r1 = gelu_tanh(r1); }
        ((float2*)(OUT + (size_t)n * D))[lane] = make_float2(r0, r1);
    }
}

// ---------------- launch ----------------

extern "C" void kernel_launch(void* const* d_in, const int* in_sizes, int n_in,
                              void* d_out, int out_size, void* d_ws, size_t ws_size,
                              hipStream_t stream) {
    const float* x    = (const float*)d_in[0];
    const int*   ei   = (const int*)d_in[1];
    const float* W    = (const float*)d_in[2];
    const float* asrc = (const float*)d_in[3];
    const float* adst = (const float*)d_in[4];
    const float* bias = (const float*)d_in[5];
    float* out = (float*)d_out;

    const int* src_arr = ei;
    const int* dst_arr = ei + NE;

    char* ws = (char*)d_ws;
    size_t off = 0;
    auto alloc = [&](size_t bytes) { char* p = ws + off; off += (bytes + 255) & ~(size_t)255; return p; };
    __half* th_a    = (__half*)alloc((size_t)NN * D * sizeof(__half));
    __half* th_b    = (__half*)alloc((size_t)NN * D * sizeof(__half));
    __half* xph     = (__half*)alloc((size_t)NN * D * sizeof(__half));
    float*  xp      = (float*)alloc((size_t)NN * D * sizeof(float));
    __half* wt      = (__half*)alloc((size_t)3 * D * D * sizeof(__half));
    float*  as_a    = (float*)alloc(NN * sizeof(float));
    float*  ad_a    = (float*)alloc(NN * sizeof(float));
    float*  as_b    = (float*)alloc(NN * sizeof(float));
    float*  ad_b    = (float*)alloc(NN * sizeof(float));
    float*  wasd    = (float*)alloc(3 * 256 * sizeof(float));
    int* counts    = (int*)alloc(NN * sizeof(int));
    int* row_ptr   = (int*)alloc((NN + 1) * sizeof(int));
    int* rank      = (int*)alloc((size_t)ETOT * sizeof(int));
    int* blk_sums  = (int*)alloc(NB * sizeof(int));
    int* blk_offs  = (int*)alloc(NB * sizeof(int));
    int* srcs      = (int*)alloc((size_t)ETOT * sizeof(int));
    (void)ws_size; (void)in_sizes; (void)n_in; (void)out_size;

    // CSR build (by dst), includes self loops — atomic-free scatter via ranks
    hipMemsetAsync(counts, 0, NN * sizeof(int), stream);
    int eb = (ETOT + 255) / 256;
    count_k<<<eb, 256, 0, stream>>>(dst_arr, counts, rank);
    scan1_k<<<NB, 256, 0, stream>>>(counts, blk_sums);
    scan2_k<<<1, 64, 0, stream>>>(blk_sums, blk_offs, row_ptr);
    scan3_k<<<NB, 256, 0, stream>>>(counts, blk_offs, row_ptr);
    scatter2_k<<<eb, 256, 0, stream>>>(src_arr, dst_arr, rank, row_ptr, srcs);

    // prep: projected attention vectors, W^T fp16, x fp16 + layer-0 alphas
    wasd_k<<<3, 256, 0, stream>>>(W, asrc, adst, wasd);
    wt_k<<<dim3(64, 3), 256, 0, stream>>>(W, wt);
    xcvt_k<<<NN / 4, 256, 0, stream>>>(x, wasd, th_a, as_a, ad_a);

    int gb = 2 * ((NN + 255) / 256);   // 392
    int ab = NN / 4;                   // 12500

    // layer 0
    gemm_mfma_k<0><<<gb, 256, 0, stream>>>(th_a, wt, xph);
    agg_half2_k<<<ab, 256, 0, stream>>>(row_ptr, srcs, as_a, ad_a, xph,
                                        bias, wasd + 256, th_b, as_b, ad_b);
    // layer 1
    gemm_mfma_k<0><<<gb, 256, 0, stream>>>(th_b, wt + 16384, xph);
    agg_half2_k<<<ab, 256, 0, stream>>>(row_ptr, srcs, as_b, ad_b, xph,
                                        bias + D, wasd + 512, th_a, as_a, ad_a);
    // layer 2: fp32 xp, fp32 out, no gelu
    gemm_mfma_k<1><<<gb, 256, 0, stream>>>(th_a, wt + 32768, xp);
    agg_k<<<ab, 256, 0, stream>>>(row_ptr, srcs, as_a, ad_a, xp,
                                  bias + 2 * D, out, 0);
}

// Round 9
// 237.870 us; speedup vs baseline: 6.7352x; 1.0904x over previous
//
#include <hip/hip_runtime.h>
#include <hip/hip_bf16.h>
#include <hip/hip_fp16.h>

#define NN    50000
#define NE    800000
#define ETOT  (NE + NN)
#define D     128
#define NB    ((NN + 255) / 256)   // scan blocks

typedef _Float16 f16x8 __attribute__((ext_vector_type(8)));
typedef float    f32x4 __attribute__((ext_vector_type(4)));

__device__ __forceinline__ float gelu_tanh(float x) {
    float x3 = x * x * x;
    float t  = tanhf(0.7978845608028654f * (x + 0.044715f * x3));
    return 0.5f * x * (1.0f + t);
}

// ---------------- CSR build ----------------

// count + rank: rank[e] = this edge's arrival index within its dst row
__global__ void count_k(const int* __restrict__ dstarr, int* __restrict__ counts,
                        int* __restrict__ rank) {
    int e = blockIdx.x * blockDim.x + threadIdx.x;
    if (e >= ETOT) return;
    int d = (e < NE) ? dstarr[e] : (e - NE);
    rank[e] = atomicAdd(&counts[d], 1);
}

__global__ void scan1_k(const int* __restrict__ counts, int* __restrict__ blk_sums) {
    __shared__ int sm[4];
    int i = blockIdx.x * 256 + threadIdx.x;
    int v = (i < NN) ? counts[i] : 0;
    #pragma unroll
    for (int o = 32; o; o >>= 1) v += __shfl_xor(v, o);
    if ((threadIdx.x & 63) == 0) sm[threadIdx.x >> 6] = v;
    __syncthreads();
    if (threadIdx.x == 0) blk_sums[blockIdx.x] = sm[0] + sm[1] + sm[2] + sm[3];
}

__global__ void scan2_k(const int* __restrict__ blk_sums, int* __restrict__ blk_offs,
                        int* __restrict__ row_ptr) {
    if (threadIdx.x == 0 && blockIdx.x == 0) {
        int acc = 0;
        for (int b = 0; b < NB; ++b) { blk_offs[b] = acc; acc += blk_sums[b]; }
        row_ptr[NN] = acc;
    }
}

__global__ void scan3_k(const int* __restrict__ counts, const int* __restrict__ blk_offs,
                        int* __restrict__ row_ptr) {
    __shared__ int s[256];
    int t = threadIdx.x;
    int i = blockIdx.x * 256 + t;
    int v = (i < NN) ? counts[i] : 0;
    s[t] = v;
    __syncthreads();
    for (int off = 1; off < 256; off <<= 1) {
        int x = (t >= off) ? s[t - off] : 0;
        __syncthreads();
        s[t] += x;
        __syncthreads();
    }
    int excl = s[t] - v + blk_offs[blockIdx.x];
    if (i < NN) row_ptr[i] = excl;
}

// atomic-free scatter: pos = row_ptr[dst] + rank
__global__ void scatter2_k(const int* __restrict__ srcarr, const int* __restrict__ dstarr,
                           const int* __restrict__ rank, const int* __restrict__ row_ptr,
                           int* __restrict__ srcs) {
    int e = blockIdx.x * blockDim.x + threadIdx.x;
    if (e >= ETOT) return;
    int d, s;
    if (e < NE) { d = dstarr[e]; s = srcarr[e]; }
    else        { d = e - NE;    s = e - NE; }
    srcs[row_ptr[d] + rank[e]] = s;
}

// ------------- wasd: per layer, was[k]=sum_c W[k][c]*as[c], wad likewise -------------

__global__ void wasd_k(const float* __restrict__ W, const float* __restrict__ asrc,
                       const float* __restrict__ adst, float* __restrict__ wasd) {
    int l = blockIdx.x;
    int t = threadIdx.x;
    int k = t & 127, which = t >> 7;
    const float* wr = W + (size_t)l * D * D + (size_t)k * D;
    const float* av = (which ? adst : asrc) + (size_t)l * D;
    float s = 0.f;
    #pragma unroll 4
    for (int c = 0; c < D; ++c) s += wr[c] * av[c];
    wasd[l * 256 + which * 128 + k] = s;
}

// ------------- wt: W[l][k][c] fp32 -> WT[l][c][k] fp16 -------------

__global__ void wt_k(const float* __restrict__ W, __half* __restrict__ WT) {
    int l = blockIdx.y;
    int i = blockIdx.x * 256 + threadIdx.x;   // 0..16383
    int k = i >> 7, c = i & 127;
    WT[(size_t)l * 16384 + (size_t)c * 128 + k] =
        __float2half_rn(W[(size_t)l * 16384 + (size_t)k * 128 + c]);
}

// ------------- xcvt: x -> fp16 table + layer-0 alphas (wave per row) -------------

__global__ __launch_bounds__(256) void xcvt_k(
        const float* __restrict__ x, const float* __restrict__ wasd0,
        __half* __restrict__ xh, float* __restrict__ alpha_s, float* __restrict__ alpha_d) {
    int n = (blockIdx.x * blockDim.x + threadIdx.x) >> 6;
    if (n >= NN) return;
    int lane = threadIdx.x & 63;
    float2 v = ((const float2*)(x + (size_t)n * D))[lane];
    ((__half2*)(xh + (size_t)n * D))[lane] = __floats2half2_rn(v.x, v.y);
    float ps = v.x * wasd0[2 * lane] + v.y * wasd0[2 * lane + 1];
    float pd = v.x * wasd0[128 + 2 * lane] + v.y * wasd0[128 + 2 * lane + 1];
    #pragma unroll
    for (int o = 32; o; o >>= 1) {
        ps += __shfl_xor(ps, o);
        pd += __shfl_xor(pd, o);
    }
    if (lane == 0) { alpha_s[n] = ps; alpha_d[n] = pd; }
}

// ------------- MFMA fp16 GEMM: XP = TH @ W (WT fp16 [c][k], LDS-staged + swizzled) -----

__global__ __launch_bounds__(256) void gemm_mfma_k(
        const __half* __restrict__ TH, const __half* __restrict__ WT,
        __half* __restrict__ XP) {
    __shared__ __half Bs[D * D];     // 32 KB, [c][k] with byte^((c&7)<<4) swizzle
    int t = threadIdx.x;
    #pragma unroll
    for (int it = 0; it < 8; ++it) {
        int b = it * 4096 + t * 16;
        int c = b >> 8;
        int swz = b ^ ((c & 7) << 4);
        *(uint4*)((char*)Bs + swz) = *(const uint4*)((const char*)WT + b);
    }
    __syncthreads();

    int w = t >> 6, lane = t & 63;
    int r0 = (blockIdx.x >> 1) * 256 + w * 64;
    int c0 = (blockIdx.x & 1) * 64;
    int lr = lane & 15, lg = lane >> 4;

    f32x4 acc[4][4];
    #pragma unroll
    for (int i = 0; i < 4; ++i)
        #pragma unroll
        for (int j = 0; j < 4; ++j)
            acc[i][j] = (f32x4){0.f, 0.f, 0.f, 0.f};

    const char* abase = (const char*)TH;
    #pragma unroll
    for (int ks = 0; ks < 4; ++ks) {
        f16x8 bf[4];
        #pragma unroll
        for (int ct = 0; ct < 4; ++ct) {
            int c  = c0 + ct * 16 + lr;
            int kb = ks * 64 + lg * 16;
            int addr = c * 256 + (kb ^ ((c & 7) << 4));
            bf[ct] = *(const f16x8*)((const char*)Bs + addr);
        }
        #pragma unroll
        for (int rt = 0; rt < 4; ++rt) {
            int row = r0 + rt * 16 + lr;
            int rc  = row < NN ? row : NN - 1;
            f16x8 af = *(const f16x8*)(abase + (size_t)rc * 256 + ks * 64 + lg * 16);
            #pragma unroll
            for (int ct = 0; ct < 4; ++ct)
                acc[rt][ct] = __builtin_amdgcn_mfma_f32_16x16x32_f16(
                                  af, bf[ct], acc[rt][ct], 0, 0, 0);
        }
    }

    #pragma unroll
    for (int rt = 0; rt < 4; ++rt) {
        #pragma unroll
        for (int q = 0; q < 4; ++q) {
            int row = r0 + rt * 16 + lg * 4 + q;
            if (row < NN) {
                #pragma unroll
                for (int ct = 0; ct < 4; ++ct) {
                    int col = c0 + ct * 16 + lr;
                    XP[(size_t)row * D + col] = __float2half_rn(acc[rt][ct][q]);
                }
            }
        }
    }
}

// ------- unified aggregation: gather fp16 xp, softmax-weighted sum, epilogue per flags ----
// OUT32: write fp32 (layer 3) vs fp16 table; GELU; HAS_NEXT: fused next-layer alphas.

template <int OUT32, int GELU, int HAS_NEXT>
__global__ __launch_bounds__(256) void agg_u_k(
        const int* __restrict__ row_ptr, const int* __restrict__ srcs,
        const float* __restrict__ alpha_s, const float* __restrict__ alpha_d,
        const __half* __restrict__ XPH, const float* __restrict__ bias,
        const float* __restrict__ wn,
        void* __restrict__ outp, float* __restrict__ as_nx, float* __restrict__ ad_nx) {
    int n = (blockIdx.x * blockDim.x + threadIdx.x) >> 6;
    int lane = threadIdx.x & 63;
    int beg = row_ptr[n], end = row_ptr[n + 1], deg = end - beg;
    float ad = alpha_d[n];
    int qw = lane >> 4, q = lane & 15;

    if (deg <= 64) {
        int sreg = 0;
        float e = -3.4e38f;
        if (lane < deg) {
            sreg = srcs[beg + lane];
            float v = alpha_s[sreg] + ad;
            e = v > 0.f ? v : 0.2f * v;
        }
        float m = e;
        #pragma unroll
        for (int o = 32; o; o >>= 1) m = fmaxf(m, __shfl_xor(m, o));
        float w = (lane < deg) ? __expf(e - m) : 0.f;
        float denom = w;
        #pragma unroll
        for (int o = 32; o; o >>= 1) denom += __shfl_xor(denom, o);

        float acc[8] = {0,0,0,0,0,0,0,0};
        int dgr = (deg + 3) & ~3;
        const uint4* base = (const uint4*)XPH;
        int j = 0;
        #define GATHER1(JOFF)                                                    \
            {                                                                    \
                int ee = j + (JOFF) + qw;                                        \
                int   ss = __shfl(sreg, ee); float ww = __shfl(w, ee);           \
                uint4 uu = base[(size_t)ss * 16 + q];                            \
                union { uint4 u; __half2 h[4]; } U; U.u = uu;                    \
                float2 f0 = __half22float2(U.h[0]);                              \
                float2 f1 = __half22float2(U.h[1]);                              \
                float2 f2 = __half22float2(U.h[2]);                              \
                float2 f3 = __half22float2(U.h[3]);                              \
                acc[0] += ww*f0.x; acc[1] += ww*f0.y;                            \
                acc[2] += ww*f1.x; acc[3] += ww*f1.y;                            \
                acc[4] += ww*f2.x; acc[5] += ww*f2.y;                            \
                acc[6] += ww*f3.x; acc[7] += ww*f3.y;                            \
            }
        for (; j + 16 <= dgr; j += 16) {
            GATHER1(0) GATHER1(4) GATHER1(8) GATHER1(12)
        }
        for (; j < dgr; j += 4) {
            GATHER1(0)
        }
        #undef GATHER1
        #pragma unroll
        for (int f = 0; f < 8; ++f) {
            acc[f] += __shfl_xor(acc[f], 16);
            acc[f] += __shfl_xor(acc[f], 32);
        }
        float inv = 1.f / (denom + 1e-16f);
        const float4* b4 = (const float4*)bias;
        float4 ba = b4[q * 2], bb = b4[q * 2 + 1];
        float rv[8];
        rv[0] = acc[0]*inv + ba.x; rv[1] = acc[1]*inv + ba.y;
        rv[2] = acc[2]*inv + ba.z; rv[3] = acc[3]*inv + ba.w;
        rv[4] = acc[4]*inv + bb.x; rv[5] = acc[5]*inv + bb.y;
        rv[6] = acc[6]*inv + bb.z; rv[7] = acc[7]*inv + bb.w;
        if (GELU) {
            #pragma unroll
            for (int f = 0; f < 8; ++f) rv[f] = gelu_tanh(rv[f]);
        }

        if (lane < 16) {
            if (OUT32) {
                float4* o = (float4*)((float*)outp + (size_t)n * D + q * 8);
                o[0] = make_float4(rv[0], rv[1], rv[2], rv[3]);
                o[1] = make_float4(rv[4], rv[5], rv[6], rv[7]);
            } else {
                union { uint4 u; __half2 h[4]; } P;
                P.h[0] = __floats2half2_rn(rv[0], rv[1]);
                P.h[1] = __floats2half2_rn(rv[2], rv[3]);
                P.h[2] = __floats2half2_rn(rv[4], rv[5]);
                P.h[3] = __floats2half2_rn(rv[6], rv[7]);
                *(uint4*)((__half*)outp + (size_t)n * D + q * 8) = P.u;
            }
        }
        if (HAS_NEXT) {
            float ps = 0.f, pd = 0.f;
            if (lane < 16) {
                const float4* w4 = (const float4*)wn;
                float4 wa = w4[q * 2], wb = w4[q * 2 + 1];
                const float4* w4d = (const float4*)(wn + 128);
                float4 wda = w4d[q * 2], wdb = w4d[q * 2 + 1];
                ps = rv[0]*wa.x + rv[1]*wa.y + rv[2]*wa.z + rv[3]*wa.w
                   + rv[4]*wb.x + rv[5]*wb.y + rv[6]*wb.z + rv[7]*wb.w;
                pd = rv[0]*wda.x + rv[1]*wda.y + rv[2]*wda.z + rv[3]*wda.w
                   + rv[4]*wdb.x + rv[5]*wdb.y + rv[6]*wdb.z + rv[7]*wdb.w;
            }
            #pragma unroll
            for (int o = 8; o; o >>= 1) {
                ps += __shfl_xor(ps, o);
                pd += __shfl_xor(pd, o);
            }
            if (lane == 0) { as_nx[n] = ps; ad_nx[n] = pd; }
        }
    } else {
        // rare fallback (deg > 64): 3-pass, 2 features per lane
        float m = -3.4e38f;
        for (int i = beg + lane; i < end; i += 64) {
            int s = srcs[i];
            float v = alpha_s[s] + ad; v = v > 0.f ? v : 0.2f * v;
            m = fmaxf(m, v);
        }
        #pragma unroll
        for (int o = 32; o; o >>= 1) m = fmaxf(m, __shfl_xor(m, o));
        float denom = 0.f;
        for (int i = beg + lane; i < end; i += 64) {
            int s = srcs[i];
            float v = alpha_s[s] + ad; v = v > 0.f ? v : 0.2f * v;
            denom += __expf(v - m);
        }
        #pragma unroll
        for (int o = 32; o; o >>= 1) denom += __shfl_xor(denom, o);
        float2 acc = {0.f, 0.f};
        for (int i = beg; i < end; ++i) {
            int s = srcs[i];
            float v = alpha_s[s] + ad; v = v > 0.f ? v : 0.2f * v;
            float wgt = __expf(v - m);
            union { unsigned int x; __half2 h; } U;
            U.x = ((const unsigned int*)(XPH + (size_t)s * D))[lane];
            float2 f = __half22float2(U.h);
            acc.x += wgt * f.x; acc.y += wgt * f.y;
        }
        float inv = 1.f / (denom + 1e-16f);
        float2 b2 = ((const float2*)bias)[lane];
        float r0 = acc.x * inv + b2.x;
        float r1 = acc.y * inv + b2.y;
        if (GELU) { r0 = gelu_tanh(r0); r1 = gelu_tanh(r1); }
        if (OUT32) {
            ((float2*)((float*)outp + (size_t)n * D))[lane] = make_float2(r0, r1);
        } else {
            ((__half2*)((__half*)outp + (size_t)n * D))[lane] = __floats2half2_rn(r0, r1);
        }
        if (HAS_NEXT) {
            float psf = r0 * wn[2 * lane] + r1 * wn[2 * lane + 1];
            float pdf = r0 * wn[128 + 2 * lane] + r1 * wn[128 + 2 * lane + 1];
            #pragma unroll
            for (int o = 32; o; o >>= 1) {
                psf += __shfl_xor(psf, o);
                pdf += __shfl_xor(pdf, o);
            }
            if (lane == 0) { as_nx[n] = psf; ad_nx[n] = pdf; }
        }
    }
}

// ---------------- launch ----------------

extern "C" void kernel_launch(void* const* d_in, const int* in_sizes, int n_in,
                              void* d_out, int out_size, void* d_ws, size_t ws_size,
                              hipStream_t stream) {
    const float* x    = (const float*)d_in[0];
    const int*   ei   = (const int*)d_in[1];
    const float* W    = (const float*)d_in[2];
    const float* asrc = (const float*)d_in[3];
    const float* adst = (const float*)d_in[4];
    const float* bias = (const float*)d_in[5];
    float* out = (float*)d_out;

    const int* src_arr = ei;
    const int* dst_arr = ei + NE;

    char* ws = (char*)d_ws;
    size_t off = 0;
    auto alloc = [&](size_t bytes) { char* p = ws + off; off += (bytes + 255) & ~(size_t)255; return p; };
    __half* th_a    = (__half*)alloc((size_t)NN * D * sizeof(__half));
    __half* th_b    = (__half*)alloc((size_t)NN * D * sizeof(__half));
    __half* xph     = (__half*)alloc((size_t)NN * D * sizeof(__half));
    __half* wt      = (__half*)alloc((size_t)3 * D * D * sizeof(__half));
    float*  as_a    = (float*)alloc(NN * sizeof(float));
    float*  ad_a    = (float*)alloc(NN * sizeof(float));
    float*  as_b    = (float*)alloc(NN * sizeof(float));
    float*  ad_b    = (float*)alloc(NN * sizeof(float));
    float*  wasd    = (float*)alloc(3 * 256 * sizeof(float));
    int* counts    = (int*)alloc(NN * sizeof(int));
    int* row_ptr   = (int*)alloc((NN + 1) * sizeof(int));
    int* rank      = (int*)alloc((size_t)ETOT * sizeof(int));
    int* blk_sums  = (int*)alloc(NB * sizeof(int));
    int* blk_offs  = (int*)alloc(NB * sizeof(int));
    int* srcs      = (int*)alloc((size_t)ETOT * sizeof(int));
    (void)ws_size; (void)in_sizes; (void)n_in; (void)out_size;

    // CSR build (by dst), includes self loops — atomic-free scatter via ranks
    hipMemsetAsync(counts, 0, NN * sizeof(int), stream);
    int eb = (ETOT + 255) / 256;
    count_k<<<eb, 256, 0, stream>>>(dst_arr, counts, rank);
    scan1_k<<<NB, 256, 0, stream>>>(counts, blk_sums);
    scan2_k<<<1, 64, 0, stream>>>(blk_sums, blk_offs, row_ptr);
    scan3_k<<<NB, 256, 0, stream>>>(counts, blk_offs, row_ptr);
    scatter2_k<<<eb, 256, 0, stream>>>(src_arr, dst_arr, rank, row_ptr, srcs);

    // prep: projected attention vectors, W^T fp16, x fp16 + layer-0 alphas
    wasd_k<<<3, 256, 0, stream>>>(W, asrc, adst, wasd);
    wt_k<<<dim3(64, 3), 256, 0, stream>>>(W, wt);
    xcvt_k<<<NN / 4, 256, 0, stream>>>(x, wasd, th_a, as_a, ad_a);

    int gb = 2 * ((NN + 255) / 256);   // 392
    int ab = NN / 4;                   // 12500

    // layer 0
    gemm_mfma_k<<<gb, 256, 0, stream>>>(th_a, wt, xph);
    agg_u_k<0, 1, 1><<<ab, 256, 0, stream>>>(row_ptr, srcs, as_a, ad_a, xph,
                                             bias, wasd + 256, th_b, as_b, ad_b);
    // layer 1
    gemm_mfma_k<<<gb, 256, 0, stream>>>(th_b, wt + 16384, xph);
    agg_u_k<0, 1, 1><<<ab, 256, 0, stream>>>(row_ptr, srcs, as_b, ad_b, xph,
                                             bias + D, wasd + 512, th_a, as_a, ad_a);
    // layer 2: fp16 table, fp32 out, no gelu, no next alphas
    gemm_mfma_k<<<gb, 256, 0, stream>>>(th_a, wt + 32768, xph);
    agg_u_k<1, 0, 0><<<ab, 256, 0, stream>>>(row_ptr, srcs, as_a, ad_a, xph,
                                             bias + 2 * D, nullptr, out, nullptr, nullptr);
}

// Round 10
// 228.353 us; speedup vs baseline: 7.0159x; 1.0417x over previous
//
#include <hip/hip_runtime.h>
#include <hip/hip_bf16.h>
#include <hip/hip_fp16.h>

#define NN    50000
#define NE    800000
#define ETOT  (NE + NN)
#define D     128
#define NB    ((NN + 255) / 256)   // scan blocks

typedef _Float16 f16x8 __attribute__((ext_vector_type(8)));
typedef float    f32x4 __attribute__((ext_vector_type(4)));

// fast tanh-gelu: gelu(x) = x - x/(exp(2z)+1), z = 0.79788456*(x+0.044715x^3)
__device__ __forceinline__ float gelu_fast(float x) {
    float x2 = x * x;
    float z2 = x * fmaf(x2, 0.07135483f, 1.5957691f);   // 2z
    float e  = __expf(z2);
    return x - __fdividef(x, e + 1.0f);
}

// ---------------- CSR build ----------------

__global__ void count_k(const int* __restrict__ dstarr, int* __restrict__ counts,
                        int* __restrict__ rank) {
    int e = blockIdx.x * blockDim.x + threadIdx.x;
    if (e >= ETOT) return;
    int d = (e < NE) ? dstarr[e] : (e - NE);
    rank[e] = atomicAdd(&counts[d], 1);
}

__global__ void scan1_k(const int* __restrict__ counts, int* __restrict__ blk_sums) {
    __shared__ int sm[4];
    int i = blockIdx.x * 256 + threadIdx.x;
    int v = (i < NN) ? counts[i] : 0;
    #pragma unroll
    for (int o = 32; o; o >>= 1) v += __shfl_xor(v, o);
    if ((threadIdx.x & 63) == 0) sm[threadIdx.x >> 6] = v;
    __syncthreads();
    if (threadIdx.x == 0) blk_sums[blockIdx.x] = sm[0] + sm[1] + sm[2] + sm[3];
}

__global__ void scan2_k(const int* __restrict__ blk_sums, int* __restrict__ blk_offs,
                        int* __restrict__ row_ptr) {
    if (threadIdx.x == 0 && blockIdx.x == 0) {
        int acc = 0;
        for (int b = 0; b < NB; ++b) { blk_offs[b] = acc; acc += blk_sums[b]; }
        row_ptr[NN] = acc;
    }
}

__global__ void scan3_k(const int* __restrict__ counts, const int* __restrict__ blk_offs,
                        int* __restrict__ row_ptr) {
    __shared__ int s[256];
    int t = threadIdx.x;
    int i = blockIdx.x * 256 + t;
    int v = (i < NN) ? counts[i] : 0;
    s[t] = v;
    __syncthreads();
    for (int off = 1; off < 256; off <<= 1) {
        int x = (t >= off) ? s[t - off] : 0;
        __syncthreads();
        s[t] += x;
        __syncthreads();
    }
    int excl = s[t] - v + blk_offs[blockIdx.x];
    if (i < NN) row_ptr[i] = excl;
}

__global__ void scatter2_k(const int* __restrict__ srcarr, const int* __restrict__ dstarr,
                           const int* __restrict__ rank, const int* __restrict__ row_ptr,
                           int* __restrict__ srcs) {
    int e = blockIdx.x * blockDim.x + threadIdx.x;
    if (e >= ETOT) return;
    int d, s;
    if (e < NE) { d = dstarr[e]; s = srcarr[e]; }
    else        { d = e - NE;    s = e - NE; }
    srcs[row_ptr[d] + rank[e]] = s;
}

// ------------- wasd: per layer, was[k]=sum_c W[k][c]*as[c], wad likewise -------------

__global__ void wasd_k(const float* __restrict__ W, const float* __restrict__ asrc,
                       const float* __restrict__ adst, float* __restrict__ wasd) {
    int l = blockIdx.x;
    int t = threadIdx.x;
    int k = t & 127, which = t >> 7;
    const float* wr = W + (size_t)l * D * D + (size_t)k * D;
    const float* av = (which ? adst : asrc) + (size_t)l * D;
    float s = 0.f;
    #pragma unroll 4
    for (int c = 0; c < D; ++c) s += wr[c] * av[c];
    wasd[l * 256 + which * 128 + k] = s;
}

// ------------- wt: W[l][k][c] fp32 -> WT[l][c][k] fp16 -------------

__global__ void wt_k(const float* __restrict__ W, __half* __restrict__ WT) {
    int l = blockIdx.y;
    int i = blockIdx.x * 256 + threadIdx.x;
    int k = i >> 7, c = i & 127;
    WT[(size_t)l * 16384 + (size_t)c * 128 + k] =
        __float2half_rn(W[(size_t)l * 16384 + (size_t)k * 128 + c]);
}

// ------------- xcvt: x -> fp16 table + layer-0 alphas (wave per row) -------------

__global__ __launch_bounds__(256) void xcvt_k(
        const float* __restrict__ x, const float* __restrict__ wasd0,
        __half* __restrict__ xh, float* __restrict__ alpha_s, float* __restrict__ alpha_d) {
    int n = (blockIdx.x * blockDim.x + threadIdx.x) >> 6;
    if (n >= NN) return;
    int lane = threadIdx.x & 63;
    float2 v = ((const float2*)(x + (size_t)n * D))[lane];
    ((__half2*)(xh + (size_t)n * D))[lane] = __floats2half2_rn(v.x, v.y);
    float ps = v.x * wasd0[2 * lane] + v.y * wasd0[2 * lane + 1];
    float pd = v.x * wasd0[128 + 2 * lane] + v.y * wasd0[128 + 2 * lane + 1];
    #pragma unroll
    for (int o = 32; o; o >>= 1) {
        ps += __shfl_xor(ps, o);
        pd += __shfl_xor(pd, o);
    }
    if (lane == 0) { alpha_s[n] = ps; alpha_d[n] = pd; }
}

// ------------- MFMA fp16 GEMM: XP = TH @ W (WT fp16 [c][k], LDS-staged + swizzled) -----

__global__ __launch_bounds__(256) void gemm_mfma_k(
        const __half* __restrict__ TH, const __half* __restrict__ WT,
        __half* __restrict__ XP) {
    __shared__ __half Bs[D * D];     // 32 KB, [c][k] with byte^((c&7)<<4) swizzle
    int t = threadIdx.x;
    #pragma unroll
    for (int it = 0; it < 8; ++it) {
        int b = it * 4096 + t * 16;
        int c = b >> 8;
        int swz = b ^ ((c & 7) << 4);
        *(uint4*)((char*)Bs + swz) = *(const uint4*)((const char*)WT + b);
    }
    __syncthreads();

    int w = t >> 6, lane = t & 63;
    int r0 = (blockIdx.x >> 1) * 256 + w * 64;
    int c0 = (blockIdx.x & 1) * 64;
    int lr = lane & 15, lg = lane >> 4;

    f32x4 acc[4][4];
    #pragma unroll
    for (int i = 0; i < 4; ++i)
        #pragma unroll
        for (int j = 0; j < 4; ++j)
            acc[i][j] = (f32x4){0.f, 0.f, 0.f, 0.f};

    const char* abase = (const char*)TH;
    #pragma unroll
    for (int ks = 0; ks < 4; ++ks) {
        f16x8 bf[4];
        #pragma unroll
        for (int ct = 0; ct < 4; ++ct) {
            int c  = c0 + ct * 16 + lr;
            int kb = ks * 64 + lg * 16;
            int addr = c * 256 + (kb ^ ((c & 7) << 4));
            bf[ct] = *(const f16x8*)((const char*)Bs + addr);
        }
        #pragma unroll
        for (int rt = 0; rt < 4; ++rt) {
            int row = r0 + rt * 16 + lr;
            int rc  = row < NN ? row : NN - 1;
            f16x8 af = *(const f16x8*)(abase + (size_t)rc * 256 + ks * 64 + lg * 16);
            #pragma unroll
            for (int ct = 0; ct < 4; ++ct)
                acc[rt][ct] = __builtin_amdgcn_mfma_f32_16x16x32_f16(
                                  af, bf[ct], acc[rt][ct], 0, 0, 0);
        }
    }

    #pragma unroll
    for (int rt = 0; rt < 4; ++rt) {
        #pragma unroll
        for (int q = 0; q < 4; ++q) {
            int row = r0 + rt * 16 + lg * 4 + q;
            if (row < NN) {
                #pragma unroll
                for (int ct = 0; ct < 4; ++ct) {
                    int col = c0 + ct * 16 + lr;
                    XP[(size_t)row * D + col] = __float2half_rn(acc[rt][ct][q]);
                }
            }
        }
    }
}

// ------- unified aggregation: gather fp16 xp, softmax-weighted sum, 2-feature epilogue ----

template <int OUT32, int GELU, int HAS_NEXT>
__global__ __launch_bounds__(256) void agg_u_k(
        const int* __restrict__ row_ptr, const int* __restrict__ srcs,
        const float* __restrict__ alpha_s, const float* __restrict__ alpha_d,
        const __half* __restrict__ XPH, const float* __restrict__ bias,
        const float* __restrict__ wn,
        void* __restrict__ outp, float* __restrict__ as_nx, float* __restrict__ ad_nx) {
    __shared__ float xch[4][128];     // 2 KB: per-wave redistribution buffer
    int wv = threadIdx.x >> 6;
    int n = (blockIdx.x * blockDim.x + threadIdx.x) >> 6;
    int lane = threadIdx.x & 63;
    int beg = row_ptr[n], end = row_ptr[n + 1], deg = end - beg;
    float ad = alpha_d[n];
    int qw = lane >> 4, q = lane & 15;

    float2 fin;   // this lane's features (2*lane, 2*lane+1), normalized (pre-bias)

    if (deg <= 64) {
        int sreg = 0;
        float e = -3.4e38f;
        if (lane < deg) {
            sreg = srcs[beg + lane];
            float v = alpha_s[sreg] + ad;
            e = v > 0.f ? v : 0.2f * v;
        }
        float m = e;
        #pragma unroll
        for (int o = 32; o; o >>= 1) m = fmaxf(m, __shfl_xor(m, o));
        float w = (lane < deg) ? __expf(e - m) : 0.f;
        float denom = w;
        #pragma unroll
        for (int o = 32; o; o >>= 1) denom += __shfl_xor(denom, o);

        float acc[8] = {0,0,0,0,0,0,0,0};
        int dgr = (deg + 3) & ~3;
        const char* xb = (const char*)XPH;
        int qb = q << 4;
        int j = 0;
        #define GATHER1(JOFF)                                                    \
            {                                                                    \
                int ee = j + (JOFF) + qw;                                        \
                int   ss = __shfl(sreg, ee); float ww = __shfl(w, ee);           \
                uint4 uu = *(const uint4*)(xb + ((ss << 8) + qb));               \
                union { uint4 u; __half2 h[4]; } U; U.u = uu;                    \
                float2 f0 = __half22float2(U.h[0]);                              \
                float2 f1 = __half22float2(U.h[1]);                              \
                float2 f2 = __half22float2(U.h[2]);                              \
                float2 f3 = __half22float2(U.h[3]);                              \
                acc[0] += ww*f0.x; acc[1] += ww*f0.y;                            \
                acc[2] += ww*f1.x; acc[3] += ww*f1.y;                            \
                acc[4] += ww*f2.x; acc[5] += ww*f2.y;                            \
                acc[6] += ww*f3.x; acc[7] += ww*f3.y;                            \
            }
        for (; j + 16 <= dgr; j += 16) {
            GATHER1(0) GATHER1(4) GATHER1(8) GATHER1(12)
        }
        for (; j < dgr; j += 4) {
            GATHER1(0)
        }
        #undef GATHER1
        #pragma unroll
        for (int f = 0; f < 8; ++f) {
            acc[f] += __shfl_xor(acc[f], 16);
            acc[f] += __shfl_xor(acc[f], 32);
        }
        // redistribute: lanes<16 own features q*8+f -> every lane owns (2l, 2l+1)
        if (lane < 16) {
            float4* p = (float4*)&xch[wv][q * 8];
            p[0] = make_float4(acc[0], acc[1], acc[2], acc[3]);
            p[1] = make_float4(acc[4], acc[5], acc[6], acc[7]);
        }
        __asm__ volatile("s_waitcnt lgkmcnt(0)" ::: "memory");
        float2 a2 = *(const float2*)&xch[wv][2 * lane];
        float inv = 1.f / (denom + 1e-16f);
        fin.x = a2.x * inv;
        fin.y = a2.y * inv;
    } else {
        // rare fallback (deg > 64): 3-pass, directly in 2-feature layout
        float m = -3.4e38f;
        for (int i = beg + lane; i < end; i += 64) {
            int s = srcs[i];
            float v = alpha_s[s] + ad; v = v > 0.f ? v : 0.2f * v;
            m = fmaxf(m, v);
        }
        #pragma unroll
        for (int o = 32; o; o >>= 1) m = fmaxf(m, __shfl_xor(m, o));
        float denom = 0.f;
        for (int i = beg + lane; i < end; i += 64) {
            int s = srcs[i];
            float v = alpha_s[s] + ad; v = v > 0.f ? v : 0.2f * v;
            denom += __expf(v - m);
        }
        #pragma unroll
        for (int o = 32; o; o >>= 1) denom += __shfl_xor(denom, o);
        float2 acc = {0.f, 0.f};
        for (int i = beg; i < end; ++i) {
            int s = srcs[i];
            float v = alpha_s[s] + ad; v = v > 0.f ? v : 0.2f * v;
            float wgt = __expf(v - m);
            union { unsigned int x; __half2 h; } U;
            U.x = ((const unsigned int*)(XPH + (size_t)s * D))[lane];
            float2 f = __half22float2(U.h);
            acc.x += wgt * f.x; acc.y += wgt * f.y;
        }
        float inv = 1.f / (denom + 1e-16f);
        fin.x = acc.x * inv;
        fin.y = acc.y * inv;
    }

    // ---- common epilogue: every lane handles features (2*lane, 2*lane+1) ----
    float2 b2 = ((const float2*)bias)[lane];
    fin.x += b2.x;
    fin.y += b2.y;
    if (GELU) { fin.x = gelu_fast(fin.x); fin.y = gelu_fast(fin.y); }

    if (OUT32) {
        ((float2*)((float*)outp + (size_t)n * D))[lane] = fin;
    } else {
        ((__half2*)((__half*)outp + (size_t)n * D))[lane] = __floats2half2_rn(fin.x, fin.y);
    }

    if (HAS_NEXT) {
        float2 ws2 = ((const float2*)wn)[lane];
        float2 wd2 = ((const float2*)(wn + 128))[lane];
        float ps = fin.x * ws2.x + fin.y * ws2.y;
        float pd = fin.x * wd2.x + fin.y * wd2.y;
        #pragma unroll
        for (int o = 32; o; o >>= 1) {
            ps += __shfl_xor(ps, o);
            pd += __shfl_xor(pd, o);
        }
        if (lane == 0) { as_nx[n] = ps; ad_nx[n] = pd; }
    }
}

// ---------------- launch ----------------

extern "C" void kernel_launch(void* const* d_in, const int* in_sizes, int n_in,
                              void* d_out, int out_size, void* d_ws, size_t ws_size,
                              hipStream_t stream) {
    const float* x    = (const float*)d_in[0];
    const int*   ei   = (const int*)d_in[1];
    const float* W    = (const float*)d_in[2];
    const float* asrc = (const float*)d_in[3];
    const float* adst = (const float*)d_in[4];
    const float* bias = (const float*)d_in[5];
    float* out = (float*)d_out;

    const int* src_arr = ei;
    const int* dst_arr = ei + NE;

    char* ws = (char*)d_ws;
    size_t off = 0;
    auto alloc = [&](size_t bytes) { char* p = ws + off; off += (bytes + 255) & ~(size_t)255; return p; };
    __half* th_a    = (__half*)alloc((size_t)NN * D * sizeof(__half));
    __half* th_b    = (__half*)alloc((size_t)NN * D * sizeof(__half));
    __half* xph     = (__half*)alloc((size_t)NN * D * sizeof(__half));
    __half* wt      = (__half*)alloc((size_t)3 * D * D * sizeof(__half));
    float*  as_a    = (float*)alloc(NN * sizeof(float));
    float*  ad_a    = (float*)alloc(NN * sizeof(float));
    float*  as_b    = (float*)alloc(NN * sizeof(float));
    float*  ad_b    = (float*)alloc(NN * sizeof(float));
    float*  wasd    = (float*)alloc(3 * 256 * sizeof(float));
    int* counts    = (int*)alloc(NN * sizeof(int));
    int* row_ptr   = (int*)alloc((NN + 1) * sizeof(int));
    int* rank      = (int*)alloc((size_t)ETOT * sizeof(int));
    int* blk_sums  = (int*)alloc(NB * sizeof(int));
    int* blk_offs  = (int*)alloc(NB * sizeof(int));
    int* srcs      = (int*)alloc((size_t)ETOT * sizeof(int));
    (void)ws_size; (void)in_sizes; (void)n_in; (void)out_size;

    // CSR build (by dst), includes self loops — atomic-free scatter via ranks
    hipMemsetAsync(counts, 0, NN * sizeof(int), stream);
    int eb = (ETOT + 255) / 256;
    count_k<<<eb, 256, 0, stream>>>(dst_arr, counts, rank);
    scan1_k<<<NB, 256, 0, stream>>>(counts, blk_sums);
    scan2_k<<<1, 64, 0, stream>>>(blk_sums, blk_offs, row_ptr);
    scan3_k<<<NB, 256, 0, stream>>>(counts, blk_offs, row_ptr);
    scatter2_k<<<eb, 256, 0, stream>>>(src_arr, dst_arr, rank, row_ptr, srcs);

    // prep: projected attention vectors, W^T fp16, x fp16 + layer-0 alphas
    wasd_k<<<3, 256, 0, stream>>>(W, asrc, adst, wasd);
    wt_k<<<dim3(64, 3), 256, 0, stream>>>(W, wt);
    xcvt_k<<<NN / 4, 256, 0, stream>>>(x, wasd, th_a, as_a, ad_a);

    int gb = 2 * ((NN + 255) / 256);   // 392
    int ab = NN / 4;                   // 12500

    // layer 0
    gemm_mfma_k<<<gb, 256, 0, stream>>>(th_a, wt, xph);
    agg_u_k<0, 1, 1><<<ab, 256, 0, stream>>>(row_ptr, srcs, as_a, ad_a, xph,
                                             bias, wasd + 256, th_b, as_b, ad_b);
    // layer 1
    gemm_mfma_k<<<gb, 256, 0, stream>>>(th_b, wt + 16384, xph);
    agg_u_k<0, 1, 1><<<ab, 256, 0, stream>>>(row_ptr, srcs, as_b, ad_b, xph,
                                             bias + D, wasd + 512, th_a, as_a, ad_a);
    // layer 2: fp16 table, fp32 out, no gelu, no next alphas
    gemm_mfma_k<<<gb, 256, 0, stream>>>(th_a, wt + 32768, xph);
    agg_u_k<1, 0, 0><<<ab, 256, 0, stream>>>(row_ptr, srcs, as_a, ad_a, xph,
                                             bias + 2 * D, nullptr, out, nullptr, nullptr);
}